// Round 5
// baseline (312.840 us; speedup 1.0000x reference)
//
#include <hip/hip_runtime.h>
#include <hip/hip_bf16.h>
#include <math.h>

typedef __bf16 bf16x8 __attribute__((ext_vector_type(8)));
typedef float f32x4 __attribute__((ext_vector_type(4)));
typedef __hip_bfloat16 bf16_t;

#define MFMA_BF16(a, b, c) __builtin_amdgcn_mfma_f32_16x16x32_bf16((a), (b), (c), 0, 0, 0)

// async global->LDS, 16B per lane; LDS dest = wave-uniform base + lane*16
__device__ __forceinline__ void async_copy16(const bf16_t* g, bf16_t* lds_base) {
  __builtin_amdgcn_global_load_lds(
      (const __attribute__((address_space(1))) unsigned int*)g,
      (__attribute__((address_space(3))) unsigned int*)lds_base,
      16, 0, 0);
}

__device__ __forceinline__ unsigned fbits(float x) { return __builtin_bit_cast(unsigned, x); }

// ---------------- fused prep: cast hidden, transpose 4 weights, concat bias ----------------
__global__ __launch_bounds__(256) void prep(
    const float* __restrict__ hidden, const float* __restrict__ Wq, const float* __restrict__ Wk,
    const float* __restrict__ Wv, const float* __restrict__ Wo,
    const float* __restrict__ bq, const float* __restrict__ bk, const float* __restrict__ bv,
    bf16_t* __restrict__ hiddenB, bf16_t* __restrict__ WqkvT, bf16_t* __restrict__ WoT,
    float* __restrict__ bqkv, float c1) {
  __shared__ float tile[64][65];
  int bid = blockIdx.x;
  const int t = threadIdx.x;
  if (bid < 8192) {  // cast hidden f32 -> bf16, float4 per thread
    const int i = bid * 256 + t;
    float4 v = ((const float4*)hidden)[i];
    union { bf16_t h[4]; ushort4 u; } cv;
    cv.h[0] = __float2bfloat16(v.x);
    cv.h[1] = __float2bfloat16(v.y);
    cv.h[2] = __float2bfloat16(v.z);
    cv.h[3] = __float2bfloat16(v.w);
    ((ushort4*)hiddenB)[i] = cv.u;
    return;
  }
  bid -= 8192;
  if (bid >= 2560) {  // bias concat: 12 blocks x 256 = 3072
    const int i = (bid - 2560) * 256 + t;
    float v;
    if (i < 2048) v = bq[i] * c1;
    else if (i < 2560) v = bk[i - 2048];
    else v = bv[i - 2560];
    bqkv[i] = v;
    return;
  }
  // weight transpose: in [2048][C] -> out [C][2048], 64x64 tiles
  const float* src;
  bf16_t* dst;
  int Cc, bx, by;
  float scale = 1.0f;
  if (bid < 1024) { src = Wq; dst = WqkvT; Cc = 2048; bx = bid & 31; by = bid >> 5; scale = c1; }
  else if (bid < 1280) { bid -= 1024; src = Wk; dst = WqkvT + (size_t)2048 * 2048; Cc = 512; bx = bid & 7; by = bid >> 3; }
  else if (bid < 1536) { bid -= 1280; src = Wv; dst = WqkvT + (size_t)2560 * 2048; Cc = 512; bx = bid & 7; by = bid >> 3; }
  else { bid -= 1536; src = Wo; dst = WoT; Cc = 2048; bx = bid & 31; by = bid >> 5; }
  const int tx = t & 63, ty = t >> 6;
  const int c0 = bx * 64, r0 = by * 64;
#pragma unroll
  for (int i = ty; i < 64; i += 4)
    tile[i][tx] = src[(size_t)(r0 + i) * Cc + c0 + tx];
  __syncthreads();
#pragma unroll
  for (int i = ty; i < 64; i += 4)
    dst[(size_t)(c0 + i) * 2048 + r0 + tx] = __float2bfloat16(tile[tx][i] * scale);
}

// ---------------- GEMM v7 (128^2, 2-barrier): kept for gemm2 ----------------
template <typename TOUT>
__global__ __launch_bounds__(256, 3) void gemm_bt(
    const bf16_t* __restrict__ A, const bf16_t* __restrict__ Bt,
    const float* __restrict__ bias, TOUT* __restrict__ C, bf16_t* __restrict__ vTp,
    int M, int N, int K) {
  __shared__ alignas(16) bf16_t As[128 * 64];
  __shared__ alignas(16) bf16_t Bs[128 * 64];

  const int tid = threadIdx.x;
  const int w = tid >> 6, lane = tid & 63;
  const int quad = lane >> 4, l16 = lane & 15;
  const int wm = w >> 1, wn = w & 1;
  const int m0 = blockIdx.y * 128, n0 = blockIdx.x * 128;

  f32x4 acc[4][4] = {};

  const int rr = lane >> 3;                 // row within 8-row staging chunk
  const int scol = ((lane & 7) ^ rr) * 8;   // swizzled SOURCE col (bf16 units)
  const int sx = l16 & 7;                   // row&7 for fragment reads

  for (int k0 = 0; k0 < K; k0 += 64) {
    __syncthreads();
#pragma unroll
    for (int c = 0; c < 4; ++c) {
      const int r = w * 32 + c * 8 + rr;
      async_copy16(A + (size_t)(m0 + r) * K + k0 + scol, &As[(w * 32 + c * 8) * 64]);
      async_copy16(Bt + (size_t)(n0 + r) * K + k0 + scol, &Bs[(w * 32 + c * 8) * 64]);
    }
    __syncthreads();

#pragma unroll
    for (int kh = 0; kh < 2; ++kh) {
      bf16x8 af[4], bf[4];
#pragma unroll
      for (int i = 0; i < 4; ++i) {
        af[i] = *(const bf16x8*)&As[(wm * 64 + i * 16 + l16) * 64 + (((kh * 4 + quad) ^ sx) * 8)];
        bf[i] = *(const bf16x8*)&Bs[(wn * 64 + i * 16 + l16) * 64 + (((kh * 4 + quad) ^ sx) * 8)];
      }
#pragma unroll
      for (int i = 0; i < 4; ++i)
#pragma unroll
        for (int j = 0; j < 4; ++j)
          acc[i][j] = MFMA_BF16(af[i], bf[j], acc[i][j]);
    }
  }

  if (vTp != nullptr && n0 >= 2560) {
#pragma unroll
    for (int i = 0; i < 4; ++i) {
      const int row = m0 + wm * 64 + i * 16 + quad * 4;
      const int bb = row >> 11, s = row & 2047;
#pragma unroll
      for (int j = 0; j < 4; ++j) {
        const int col = n0 + wn * 64 + j * 16 + l16;
        const float bv = bias[col];
        union { bf16_t h[4]; ushort4 u; } cv;
#pragma unroll
        for (int r = 0; r < 4; ++r) cv.h[r] = __float2bfloat16(acc[i][j][r] + bv);
        *(ushort4*)&vTp[((size_t)bb * 512 + (col - 2560)) * 2048 + s] = cv.u;
      }
    }
    return;
  }

#pragma unroll
  for (int i = 0; i < 4; ++i) {
    const int row = m0 + wm * 64 + i * 16 + quad * 4;
#pragma unroll
    for (int j = 0; j < 4; ++j) {
      const int col = n0 + wn * 64 + j * 16 + l16;
      const float bv = bias[col];
#pragma unroll
      for (int r = 0; r < 4; ++r) {
        const float val = acc[i][j][r] + bv;
        if constexpr (__is_same(TOUT, float)) {
          C[(size_t)(row + r) * N + col] = val;
        } else {
          C[(size_t)(row + r) * N + col] = __float2bfloat16(val);
        }
      }
    }
  }
}

// ---------------- GEMM v9.2: 256^2 8-phase counted-vmcnt (T1+T2+T3+T4+T5) ----------------
// Kept unchanged this round (R3/R4 both ~flat vs gemm_bt; this round's attn split will
// surface its counters in top-5 for the first time -> diagnose occupancy/MfmaUtil directly).
__global__ __launch_bounds__(512, 2) void gemm256(
    const bf16_t* __restrict__ A, const bf16_t* __restrict__ Bt,
    const float* __restrict__ bias, bf16_t* __restrict__ C, bf16_t* __restrict__ vTp) {
  constexpr int N = 3072, K = 2048;
  __shared__ alignas(16) bf16_t As[2 * 256 * 64];
  __shared__ alignas(16) bf16_t Bs[2 * 256 * 64];

  const int tid = threadIdx.x;
  const int w = tid >> 6, lane = tid & 63;
  const int quad = lane >> 4, l16 = lane & 15;
  const int wm = w >> 2, wn = w & 3;

  // T1: XCD-aware swizzle. flat = y*12+x; swz = (flat%8)*24 + flat/8 (bijective, 192%8==0)
  const int flat = blockIdx.y * 12 + blockIdx.x;
  const int swz = (flat & 7) * 24 + (flat >> 3);
  const int m0 = (swz / 12) * 256, n0 = (swz % 12) * 256;

  const int rr = lane >> 3, c7 = lane & 7;
  const int scol = (c7 ^ rr) * 8;  // inverse-swizzled SOURCE col (bf16 units)
  const int sx = l16 & 7;          // row&7 for fragment reads

  // stage one 128-row half-tile (2 x global_load_lds per wave)
  auto stA = [&](int t, int h) {
    const int kb = (t & 31) * 64;
    const int rbase = h * 128 + w * 8;
    bf16_t* d0 = &As[(t & 1) * (256 * 64) + rbase * 64];
    const bf16_t* s0 = A + (size_t)(m0 + rbase + rr) * K + kb + scol;
    async_copy16(s0, d0);
    async_copy16(s0 + (size_t)64 * K, d0 + 64 * 64);
  };
  auto stB = [&](int t, int h) {
    const int kb = (t & 31) * 64;
    const int rbase = h * 128 + w * 8;
    bf16_t* d0 = &Bs[(t & 1) * (256 * 64) + rbase * 64];
    const bf16_t* s0 = Bt + (size_t)(n0 + rbase + rr) * K + kb + scol;
    async_copy16(s0, d0);
    async_copy16(s0 + (size_t)64 * K, d0 + 64 * 64);
  };

  f32x4 acc[4][2][4] = {};  // [phase/quadrant][mi][ni]

  // prologue: tile0 fully staged, tile1.B in flight (newest 4 loads) -> vmcnt(4)
  stB(0, 0); stB(0, 1); stA(0, 0); stA(0, 1);
  stB(1, 0); stB(1, 1);
  asm volatile("s_waitcnt vmcnt(4)" ::: "memory");
  __builtin_amdgcn_s_barrier();
  __builtin_amdgcn_sched_barrier(0);  // publish barrier: tile0 read immediately below

  for (int it = 0; it < 16; ++it) {
    const int kt = it * 2;
#pragma unroll
    for (int kg = 0; kg < 2; ++kg) {
      const int ta = (kt + kg + 1) & 31;  // stA target tile
      const int tb = (kt + kg + 2) & 31;  // stB target tile
      const bf16_t* Asb = &As[kg * (256 * 64)];
      const bf16_t* Bsb = &Bs[kg * (256 * 64)];
      bf16x8 b[4][2];
#pragma unroll
      for (int p = 0; p < 4; ++p) {
        // ---- ds reads (C++-level: compiler inserts fine-grained lgkmcnt) ----
        if (p == 0) {
#pragma unroll
          for (int ni = 0; ni < 4; ++ni)
#pragma unroll
            for (int kk = 0; kk < 2; ++kk)
              b[ni][kk] = *(const bf16x8*)&Bsb[(wn * 64 + ni * 16 + l16) * 64 +
                                               (((kk * 4 + quad) ^ sx) * 8)];
        }
        bf16x8 a[2][2];
#pragma unroll
        for (int mi = 0; mi < 2; ++mi)
#pragma unroll
          for (int kk = 0; kk < 2; ++kk)
            a[mi][kk] = *(const bf16x8*)&Asb[(wm * 128 + p * 32 + mi * 16 + l16) * 64 +
                                             (((kk * 4 + quad) ^ sx) * 8)];
        // ---- stage slot (1 half-tile) ----
        if (p == 0) stA(ta, 0);
        else if (p == 1) stA(ta, 1);
        else if (p == 2) stB(tb, 0);
        else stB(tb, 1);
        __builtin_amdgcn_s_barrier();
        __builtin_amdgcn_s_setprio(1);
#pragma unroll
        for (int kk = 0; kk < 2; ++kk)
#pragma unroll
          for (int mi = 0; mi < 2; ++mi)
#pragma unroll
            for (int ni = 0; ni < 4; ++ni)
              acc[p][mi][ni] = MFMA_BF16(a[mi][kk], b[ni][kk], acc[p][mi][ni]);
        __builtin_amdgcn_s_setprio(0);
        if (p == 3) {
          // counted drain: 4 newest loads (the 2 B half-tiles just issued) stay in flight
          asm volatile("s_waitcnt vmcnt(4)" ::: "memory");
          __builtin_amdgcn_s_barrier();
          __builtin_amdgcn_sched_barrier(0);  // publish barrier: next phase reads now
        } else {
          __builtin_amdgcn_s_barrier();
        }
      }
    }
  }

  // drain staging loads before LDS goes away / epilogue
  asm volatile("s_waitcnt vmcnt(0)" ::: "memory");

  if (n0 >= 2560) {
    // v-columns -> vT[b][col-2560][s]; rows are b*2048+s, 4 consecutive s per lane
#pragma unroll
    for (int p = 0; p < 4; ++p)
#pragma unroll
      for (int mi = 0; mi < 2; ++mi) {
        const int row4 = m0 + wm * 128 + p * 32 + mi * 16 + quad * 4;
        const int bb = row4 >> 11, s = row4 & 2047;
#pragma unroll
        for (int ni = 0; ni < 4; ++ni) {
          const int col = n0 + wn * 64 + ni * 16 + l16;
          const float bv = bias[col];
          union { bf16_t h[4]; ushort4 u; } cv;
#pragma unroll
          for (int r = 0; r < 4; ++r) cv.h[r] = __float2bfloat16(acc[p][mi][ni][r] + bv);
          *(ushort4*)&vTp[((size_t)bb * 512 + (col - 2560)) * 2048 + s] = cv.u;
        }
      }
    return;
  }

#pragma unroll
  for (int p = 0; p < 4; ++p)
#pragma unroll
    for (int mi = 0; mi < 2; ++mi) {
      const int row4 = m0 + wm * 128 + p * 32 + mi * 16 + quad * 4;
#pragma unroll
      for (int ni = 0; ni < 4; ++ni) {
        const int col = n0 + wn * 64 + ni * 16 + l16;
        const float bv = bias[col];
#pragma unroll
        for (int r = 0; r < 4; ++r)
          C[(size_t)(row4 + r) * N + col] = __float2bfloat16(acc[p][mi][ni][r] + bv);
      }
    }
}

// ---------------- GQA flash attention (v8.1: split-grid for rocprof visibility) ----------------
// Identical math to v8 (R2: 88.2->81.0 us). This round the kernel is launched TWICE with
// xoff = 0 and 16 (q-blocks 0..15 / 16..31). Each block still runs the FULL S loop, so
// online-softmax normalization and outputs are unchanged; output ranges are disjoint.
// Purpose: drop per-dispatch duration below the gemms so they surface in rocprof top-5
// (R2-R4: attn monopolized all slots; gemm durations never observed). Cost: 2 blocks/CU
// per dispatch instead of 4 (~+8-15 us total) — accepted once for measurement.
__global__ __launch_bounds__(256, 4) void gqa_attn(
    const bf16_t* __restrict__ QKV, const bf16_t* __restrict__ VT, bf16_t* __restrict__ O,
    int xoff) {
  constexpr int S = 2048, HID = 2048, QKVS = 3072, HD = 64;
  const int tid = threadIdx.x;
  const int w = tid >> 6, lane = tid & 63;
  const int quad = lane >> 4, l16 = lane & 15;
  const int hp = blockIdx.y, b = blockIdx.z;
  const int h = hp * 2 + (w & 1);       // wave's head
  const int g = hp >> 1;                // shared KV group (rep=4: heads 4g..4g+3)
  const int q0 = (xoff + blockIdx.x) * 64 + (w >> 1) * 32;  // wave's 32 q rows

  __shared__ alignas(16) bf16_t Ks[64 * 64];
  __shared__ alignas(16) bf16_t VTs[64 * 64];
  __shared__ alignas(16) bf16_t Ps[128 * 64];

  // Q fragments in registers (B-operand layout: n=l16 -> q, k=quad*8+j); pre-scaled
  bf16x8 qf[2][2];
#pragma unroll
  for (int mt = 0; mt < 2; ++mt)
#pragma unroll
    for (int ks = 0; ks < 2; ++ks)
      qf[mt][ks] = *(const bf16x8*)&QKV[(size_t)(b * S + q0 + mt * 16 + l16) * QKVS +
                                        h * HD + ks * 32 + quad * 8];

  const int rr = lane >> 3, c7 = lane & 7;
  const int sx = l16 & 7;

  const bf16_t* Kbase = QKV + (size_t)b * S * QKVS + 2048 + g * HD;
  const bf16_t* Vbase = VT + (size_t)(b * 512 + g * HD) * S;

  // reg-staging geometry: this thread owns rows srow and srow+8 of the 64-row tile,
  // 16B chunk c7; LDS dest chunk XOR-swizzled with row&7 (= rr).
  const int srow = w * 16 + rr;
  const bf16_t* kp0 = Kbase + (size_t)srow * QKVS + c7 * 8;
  const bf16_t* kp1 = kp0 + (size_t)8 * QKVS;
  const bf16_t* vp0 = Vbase + (size_t)srow * S + c7 * 8;
  const bf16_t* vp1 = vp0 + (size_t)8 * S;
  bf16_t* KsW0 = &Ks[(srow)*64 + (c7 ^ rr) * 8];
  bf16_t* KsW1 = KsW0 + 8 * 64;
  bf16_t* VsW0 = &VTs[(srow)*64 + (c7 ^ rr) * 8];
  bf16_t* VsW1 = VsW0 + 8 * 64;

  f32x4 oacc[2][4] = {};
  f32x4 lacc[2] = {};
  bf16x8 ones;
#pragma unroll
  for (int j = 0; j < 8; ++j) ones[j] = (__bf16)1.0f;

  // prologue: issue tile-0 loads
  uint4 kr0 = *(const uint4*)kp0;
  uint4 kr1 = *(const uint4*)kp1;
  uint4 vr0 = *(const uint4*)vp0;
  uint4 vr1 = *(const uint4*)vp1;

  for (int s0 = 0; s0 < S; s0 += 64) {
    __syncthreads();  // all waves done reading the previous tile's LDS
    *(uint4*)KsW0 = kr0;
    *(uint4*)KsW1 = kr1;
    *(uint4*)VsW0 = vr0;
    *(uint4*)VsW1 = vr1;
    // issue next-tile loads now; they stay in flight across the whole compute phase.
    const int sn = (s0 + 64) & (S - 1);
    kr0 = *(const uint4*)(kp0 + (size_t)sn * QKVS);
    kr1 = *(const uint4*)(kp1 + (size_t)sn * QKVS);
    vr0 = *(const uint4*)(vp0 + sn);
    vr1 = *(const uint4*)(vp1 + sn);
    __syncthreads();  // ds_writes visible to all waves

    __builtin_amdgcn_s_setprio(1);
    // ---- S^T = K·Q^T (row=kv=quad*4+r, col=q=l16); p=exp2(s); pack(trunc) -> Ps[q][kv] ----
#pragma unroll
    for (int nt = 0; nt < 4; ++nt) {
      bf16x8 kf0 = *(const bf16x8*)&Ks[(nt * 16 + l16) * 64 + ((quad ^ sx) * 8)];
      bf16x8 kf1 = *(const bf16x8*)&Ks[(nt * 16 + l16) * 64 + (((4 + quad) ^ sx) * 8)];
#pragma unroll
      for (int mt = 0; mt < 2; ++mt) {
        f32x4 s = {};
        s = MFMA_BF16(kf0, qf[mt][0], s);
        s = MFMA_BF16(kf1, qf[mt][1], s);
        const float p0 = __builtin_amdgcn_exp2f(s[0]);
        const float p1 = __builtin_amdgcn_exp2f(s[1]);
        const float p2 = __builtin_amdgcn_exp2f(s[2]);
        const float p3 = __builtin_amdgcn_exp2f(s[3]);
        uint2 pk;
        pk.x = __builtin_amdgcn_perm(fbits(p1), fbits(p0), 0x07060302);  // [bf16(p1)|bf16(p0)]
        pk.y = __builtin_amdgcn_perm(fbits(p3), fbits(p2), 0x07060302);
        *(uint2*)&Ps[(w * 32 + mt * 16 + l16) * 64 +
                     (((nt * 2 + (quad >> 1)) ^ sx) * 8) + (quad & 1) * 4] = pk;
      }
    }

    // ---- O += P·V; row-sums via ones-B MFMA (sums truncated bf16 P -> bias cancels) ----
#pragma unroll
    for (int kc = 0; kc < 2; ++kc) {
      bf16x8 pf[2];
#pragma unroll
      for (int mt = 0; mt < 2; ++mt) {
        pf[mt] = *(const bf16x8*)&Ps[(w * 32 + mt * 16 + l16) * 64 + (((kc * 4 + quad) ^ sx) * 8)];
        lacc[mt] = MFMA_BF16(pf[mt], ones, lacc[mt]);
      }
#pragma unroll
      for (int dt = 0; dt < 4; ++dt) {
        bf16x8 vf = *(const bf16x8*)&VTs[(dt * 16 + l16) * 64 + (((kc * 4 + quad) ^ sx) * 8)];
#pragma unroll
        for (int mt = 0; mt < 2; ++mt)
          oacc[mt][dt] = MFMA_BF16(pf[mt], vf, oacc[mt][dt]);
      }
    }
    __builtin_amdgcn_s_setprio(0);
  }

  // ---- normalize + store ----
#pragma unroll
  for (int mt = 0; mt < 2; ++mt) {
    float linv[4];
#pragma unroll
    for (int r = 0; r < 4; ++r) linv[r] = 1.0f / lacc[mt][r];
#pragma unroll
    for (int dt = 0; dt < 4; ++dt)
#pragma unroll
      for (int r = 0; r < 4; ++r)
        O[(size_t)(b * S + q0 + mt * 16 + quad * 4 + r) * HID + h * HD + dt * 16 + l16] =
            __float2bfloat16(oacc[mt][dt][r] * linv[r]);
  }
}

extern "C" void kernel_launch(void* const* d_in, const int* in_sizes, int n_in,
                              void* d_out, int out_size, void* d_ws, size_t ws_size,
                              hipStream_t stream) {
  const float* hidden = (const float*)d_in[0];
  const float* Wq = (const float*)d_in[1];
  const float* bq = (const float*)d_in[2];
  const float* Wk = (const float*)d_in[3];
  const float* bk = (const float*)d_in[4];
  const float* Wv = (const float*)d_in[5];
  const float* bv = (const float*)d_in[6];
  const float* Wo = (const float*)d_in[7];
  const float* bo = (const float*)d_in[8];
  float* out = (float*)d_out;

  constexpr int B = 2, S = 2048, HID = 2048, KV = 512, QKVN = 3072;
  constexpr int M = B * S;  // 4096
  const float c1 = 0.125f * 1.44269504089f;

  char* ws = (char*)d_ws;
  bf16_t* hiddenB = (bf16_t*)ws; ws += (size_t)M * HID * 2;
  bf16_t* WqkvT = (bf16_t*)ws;   ws += (size_t)QKVN * HID * 2;
  bf16_t* WoT = (bf16_t*)ws;     ws += (size_t)HID * HID * 2;
  bf16_t* qkv = (bf16_t*)ws;     ws += (size_t)M * QKVN * 2;
  bf16_t* vT = (bf16_t*)ws;      ws += (size_t)M * KV * 2;
  bf16_t* attn = (bf16_t*)ws;    ws += (size_t)M * HID * 2;
  float* bqkv = (float*)ws;      ws += QKVN * 4;

  // one fused prep launch: cast + 4 weight transposes (64x64 tiles) + bias concat
  prep<<<8192 + 2560 + 12, 256, 0, stream>>>(hidden, Wq, Wk, Wv, Wo, bq, bk, bv,
                                             hiddenB, WqkvT, WoT, bqkv, c1);

  // QKV projection: 256^2 8-phase kernel; v-columns written transposed to vT
  gemm256<<<dim3(QKVN / 256, M / 256), 512, 0, stream>>>(hiddenB, WqkvT, bqkv, qkv, vT);

  // attention split into two half-grids (instrumentation round: surface gemm counters)
  gqa_attn<<<dim3(S / 128, 16, B), 256, 0, stream>>>(qkv, vT, attn, 0);
  gqa_attn<<<dim3(S / 128, 16, B), 256, 0, stream>>>(qkv, vT, attn, 16);

  gemm_bt<float><<<dim3(HID / 128, M / 128), 256, 0, stream>>>(
      attn, WoT, bo, out, (bf16_t*)nullptr, M, HID, HID);
}

// Round 6
// 311.190 us; speedup vs baseline: 1.0053x; 1.0053x over previous
//
#include <hip/hip_runtime.h>
#include <hip/hip_bf16.h>
#include <math.h>

typedef __bf16 bf16x8 __attribute__((ext_vector_type(8)));
typedef float f32x4 __attribute__((ext_vector_type(4)));
typedef __hip_bfloat16 bf16_t;

#define MFMA_BF16(a, b, c) __builtin_amdgcn_mfma_f32_16x16x32_bf16((a), (b), (c), 0, 0, 0)

// async global->LDS, 16B per lane; LDS dest = wave-uniform base + lane*16
__device__ __forceinline__ void async_copy16(const bf16_t* g, bf16_t* lds_base) {
  __builtin_amdgcn_global_load_lds(
      (const __attribute__((address_space(1))) unsigned int*)g,
      (__attribute__((address_space(3))) unsigned int*)lds_base,
      16, 0, 0);
}

__device__ __forceinline__ unsigned fbits(float x) { return __builtin_bit_cast(unsigned, x); }

// ---------------- fused prep: cast hidden, transpose 4 weights, concat bias ----------------
__global__ __launch_bounds__(256) void prep(
    const float* __restrict__ hidden, const float* __restrict__ Wq, const float* __restrict__ Wk,
    const float* __restrict__ Wv, const float* __restrict__ Wo,
    const float* __restrict__ bq, const float* __restrict__ bk, const float* __restrict__ bv,
    bf16_t* __restrict__ hiddenB, bf16_t* __restrict__ WqkvT, bf16_t* __restrict__ WoT,
    float* __restrict__ bqkv, float c1) {
  __shared__ float tile[64][65];
  int bid = blockIdx.x;
  const int t = threadIdx.x;
  if (bid < 8192) {  // cast hidden f32 -> bf16, float4 per thread
    const int i = bid * 256 + t;
    float4 v = ((const float4*)hidden)[i];
    union { bf16_t h[4]; ushort4 u; } cv;
    cv.h[0] = __float2bfloat16(v.x);
    cv.h[1] = __float2bfloat16(v.y);
    cv.h[2] = __float2bfloat16(v.z);
    cv.h[3] = __float2bfloat16(v.w);
    ((ushort4*)hiddenB)[i] = cv.u;
    return;
  }
  bid -= 8192;
  if (bid >= 2560) {  // bias concat: 12 blocks x 256 = 3072
    const int i = (bid - 2560) * 256 + t;
    float v;
    if (i < 2048) v = bq[i] * c1;
    else if (i < 2560) v = bk[i - 2048];
    else v = bv[i - 2560];
    bqkv[i] = v;
    return;
  }
  // weight transpose: in [2048][C] -> out [C][2048], 64x64 tiles
  const float* src;
  bf16_t* dst;
  int Cc, bx, by;
  float scale = 1.0f;
  if (bid < 1024) { src = Wq; dst = WqkvT; Cc = 2048; bx = bid & 31; by = bid >> 5; scale = c1; }
  else if (bid < 1280) { bid -= 1024; src = Wk; dst = WqkvT + (size_t)2048 * 2048; Cc = 512; bx = bid & 7; by = bid >> 3; }
  else if (bid < 1536) { bid -= 1280; src = Wv; dst = WqkvT + (size_t)2560 * 2048; Cc = 512; bx = bid & 7; by = bid >> 3; }
  else { bid -= 1536; src = Wo; dst = WoT; Cc = 2048; bx = bid & 31; by = bid >> 5; }
  const int tx = t & 63, ty = t >> 6;
  const int c0 = bx * 64, r0 = by * 64;
#pragma unroll
  for (int i = ty; i < 64; i += 4)
    tile[i][tx] = src[(size_t)(r0 + i) * Cc + c0 + tx];
  __syncthreads();
#pragma unroll
  for (int i = ty; i < 64; i += 4)
    dst[(size_t)(c0 + i) * 2048 + r0 + tx] = __float2bfloat16(tile[tx][i] * scale);
}

// ---------------- GEMM v7 (128^2, 2-barrier): kept for gemm2 ----------------
template <typename TOUT>
__global__ __launch_bounds__(256, 3) void gemm_bt(
    const bf16_t* __restrict__ A, const bf16_t* __restrict__ Bt,
    const float* __restrict__ bias, TOUT* __restrict__ C, bf16_t* __restrict__ vTp,
    int M, int N, int K) {
  __shared__ alignas(16) bf16_t As[128 * 64];
  __shared__ alignas(16) bf16_t Bs[128 * 64];

  const int tid = threadIdx.x;
  const int w = tid >> 6, lane = tid & 63;
  const int quad = lane >> 4, l16 = lane & 15;
  const int wm = w >> 1, wn = w & 1;
  const int m0 = blockIdx.y * 128, n0 = blockIdx.x * 128;

  f32x4 acc[4][4] = {};

  const int rr = lane >> 3;                 // row within 8-row staging chunk
  const int scol = ((lane & 7) ^ rr) * 8;   // swizzled SOURCE col (bf16 units)
  const int sx = l16 & 7;                   // row&7 for fragment reads

  for (int k0 = 0; k0 < K; k0 += 64) {
    __syncthreads();
#pragma unroll
    for (int c = 0; c < 4; ++c) {
      const int r = w * 32 + c * 8 + rr;
      async_copy16(A + (size_t)(m0 + r) * K + k0 + scol, &As[(w * 32 + c * 8) * 64]);
      async_copy16(Bt + (size_t)(n0 + r) * K + k0 + scol, &Bs[(w * 32 + c * 8) * 64]);
    }
    __syncthreads();

#pragma unroll
    for (int kh = 0; kh < 2; ++kh) {
      bf16x8 af[4], bf[4];
#pragma unroll
      for (int i = 0; i < 4; ++i) {
        af[i] = *(const bf16x8*)&As[(wm * 64 + i * 16 + l16) * 64 + (((kh * 4 + quad) ^ sx) * 8)];
        bf[i] = *(const bf16x8*)&Bs[(wn * 64 + i * 16 + l16) * 64 + (((kh * 4 + quad) ^ sx) * 8)];
      }
#pragma unroll
      for (int i = 0; i < 4; ++i)
#pragma unroll
        for (int j = 0; j < 4; ++j)
          acc[i][j] = MFMA_BF16(af[i], bf[j], acc[i][j]);
    }
  }

  if (vTp != nullptr && n0 >= 2560) {
#pragma unroll
    for (int i = 0; i < 4; ++i) {
      const int row = m0 + wm * 64 + i * 16 + quad * 4;
      const int bb = row >> 11, s = row & 2047;
#pragma unroll
      for (int j = 0; j < 4; ++j) {
        const int col = n0 + wn * 64 + j * 16 + l16;
        const float bv = bias[col];
        union { bf16_t h[4]; ushort4 u; } cv;
#pragma unroll
        for (int r = 0; r < 4; ++r) cv.h[r] = __float2bfloat16(acc[i][j][r] + bv);
        *(ushort4*)&vTp[((size_t)bb * 512 + (col - 2560)) * 2048 + s] = cv.u;
      }
    }
    return;
  }

#pragma unroll
  for (int i = 0; i < 4; ++i) {
    const int row = m0 + wm * 64 + i * 16 + quad * 4;
#pragma unroll
    for (int j = 0; j < 4; ++j) {
      const int col = n0 + wn * 64 + j * 16 + l16;
      const float bv = bias[col];
#pragma unroll
      for (int r = 0; r < 4; ++r) {
        const float val = acc[i][j][r] + bv;
        if constexpr (__is_same(TOUT, float)) {
          C[(size_t)(row + r) * N + col] = val;
        } else {
          C[(size_t)(row + r) * N + col] = __float2bfloat16(val);
        }
      }
    }
  }
}

// ---------------- GEMM v9.3: 256^2, 2 mega-phases per K-tile (halved barrier count) ----------------
// R5 diagnosis: 68.9us = 1292 cyc/phase, MFMA issue duty only ~12%, LDS-read ~45%,
// bank-conflicts 0 -> ~500+ cyc/phase FIXED overhead; 3 different schedules all ~69us
// => per-phase overhead (barrier rendezvous chains), not instruction order, is the binder.
// v9.3: merge phase pairs -> 2 mega-phases per K-tile (4 barriers/kt -> 2... 4->... 8->4
// per 2 K-tiles), KEEPING the ds_read || stage || MFMA interleave inside each mega-phase
// (m196: losing the interleave is what hurts).
//   mp0: read B(t)+A-quadrants 0,1 ; stage A(t+1) h0,h1 ; barrier ; 32 MFMA ; barrier
//   mp1: read A-quadrants 2,3      ; stage B(t+2) h0,h1 ; barrier ; 32 MFMA ; vmcnt(4); barrier
// Race-free: stage targets' last reads completed >=2 barriers before the stage lands
// (A(t+1)->opposite buf, last read prev kg; B(t+2)->current B buf, read into regs at mp0).
// Drain: at kg end outstanding 12 -> vmcnt(4) waits B(t+1)+A(t+1) (needed next kg),
// leaves B(t+2) in flight with 2 K-tiles of latency cover.
__global__ __launch_bounds__(512, 2) void gemm256(
    const bf16_t* __restrict__ A, const bf16_t* __restrict__ Bt,
    const float* __restrict__ bias, bf16_t* __restrict__ C, bf16_t* __restrict__ vTp) {
  constexpr int N = 3072, K = 2048;
  __shared__ alignas(16) bf16_t As[2 * 256 * 64];
  __shared__ alignas(16) bf16_t Bs[2 * 256 * 64];

  const int tid = threadIdx.x;
  const int w = tid >> 6, lane = tid & 63;
  const int quad = lane >> 4, l16 = lane & 15;
  const int wm = w >> 2, wn = w & 3;

  // T1: XCD-aware swizzle. flat = y*12+x; swz = (flat%8)*24 + flat/8 (bijective, 192%8==0)
  const int flat = blockIdx.y * 12 + blockIdx.x;
  const int swz = (flat & 7) * 24 + (flat >> 3);
  const int m0 = (swz / 12) * 256, n0 = (swz % 12) * 256;

  const int rr = lane >> 3, c7 = lane & 7;
  const int scol = (c7 ^ rr) * 8;  // inverse-swizzled SOURCE col (bf16 units)
  const int sx = l16 & 7;          // row&7 for fragment reads

  // stage one 128-row half-tile (2 x global_load_lds per wave)
  auto stA = [&](int t, int h) {
    const int kb = (t & 31) * 64;
    const int rbase = h * 128 + w * 8;
    bf16_t* d0 = &As[(t & 1) * (256 * 64) + rbase * 64];
    const bf16_t* s0 = A + (size_t)(m0 + rbase + rr) * K + kb + scol;
    async_copy16(s0, d0);
    async_copy16(s0 + (size_t)64 * K, d0 + 64 * 64);
  };
  auto stB = [&](int t, int h) {
    const int kb = (t & 31) * 64;
    const int rbase = h * 128 + w * 8;
    bf16_t* d0 = &Bs[(t & 1) * (256 * 64) + rbase * 64];
    const bf16_t* s0 = Bt + (size_t)(n0 + rbase + rr) * K + kb + scol;
    async_copy16(s0, d0);
    async_copy16(s0 + (size_t)64 * K, d0 + 64 * 64);
  };

  f32x4 acc[4][2][4] = {};  // [quadrant][mi][ni]

  // prologue: tile0 fully staged, tile1.B in flight (newest 4 loads) -> vmcnt(4)
  stB(0, 0); stB(0, 1); stA(0, 0); stA(0, 1);
  stB(1, 0); stB(1, 1);
  asm volatile("s_waitcnt vmcnt(4)" ::: "memory");
  __builtin_amdgcn_s_barrier();
  __builtin_amdgcn_sched_barrier(0);  // publish barrier: tile0 read immediately below

  for (int it = 0; it < 16; ++it) {
#pragma unroll
    for (int kg = 0; kg < 2; ++kg) {
      const int t = it * 2 + kg;
      const int ta = (t + 1) & 31;  // stA target tile
      const int tb = (t + 2) & 31;  // stB target tile
      const bf16_t* Asb = &As[(t & 1) * (256 * 64)];
      const bf16_t* Bsb = &Bs[(t & 1) * (256 * 64)];

      // ---- mega-phase 0: B + A-quadrants 0,1 ; stage A(t+1) ----
      bf16x8 b[4][2];
#pragma unroll
      for (int ni = 0; ni < 4; ++ni)
#pragma unroll
        for (int kk = 0; kk < 2; ++kk)
          b[ni][kk] = *(const bf16x8*)&Bsb[(wn * 64 + ni * 16 + l16) * 64 +
                                           (((kk * 4 + quad) ^ sx) * 8)];
      bf16x8 a01[2][2][2];
#pragma unroll
      for (int p = 0; p < 2; ++p)
#pragma unroll
        for (int mi = 0; mi < 2; ++mi)
#pragma unroll
          for (int kk = 0; kk < 2; ++kk)
            a01[p][mi][kk] = *(const bf16x8*)&Asb[(wm * 128 + p * 32 + mi * 16 + l16) * 64 +
                                                  (((kk * 4 + quad) ^ sx) * 8)];
      stA(ta, 0); stA(ta, 1);
      __builtin_amdgcn_s_barrier();
      __builtin_amdgcn_s_setprio(1);
#pragma unroll
      for (int p = 0; p < 2; ++p)
#pragma unroll
        for (int kk = 0; kk < 2; ++kk)
#pragma unroll
          for (int mi = 0; mi < 2; ++mi)
#pragma unroll
            for (int ni = 0; ni < 4; ++ni)
              acc[p][mi][ni] = MFMA_BF16(a01[p][mi][kk], b[ni][kk], acc[p][mi][ni]);
      __builtin_amdgcn_s_setprio(0);
      __builtin_amdgcn_s_barrier();

      // ---- mega-phase 1: A-quadrants 2,3 ; stage B(t+2) ; drain ----
      bf16x8 a23[2][2][2];
#pragma unroll
      for (int p = 0; p < 2; ++p)
#pragma unroll
        for (int mi = 0; mi < 2; ++mi)
#pragma unroll
          for (int kk = 0; kk < 2; ++kk)
            a23[p][mi][kk] = *(const bf16x8*)&Asb[(wm * 128 + (p + 2) * 32 + mi * 16 + l16) * 64 +
                                                  (((kk * 4 + quad) ^ sx) * 8)];
      stB(tb, 0); stB(tb, 1);
      __builtin_amdgcn_s_barrier();
      __builtin_amdgcn_s_setprio(1);
#pragma unroll
      for (int p = 0; p < 2; ++p)
#pragma unroll
        for (int kk = 0; kk < 2; ++kk)
#pragma unroll
          for (int mi = 0; mi < 2; ++mi)
#pragma unroll
            for (int ni = 0; ni < 4; ++ni)
              acc[p + 2][mi][ni] = MFMA_BF16(a23[p][mi][kk], b[ni][kk], acc[p + 2][mi][ni]);
      __builtin_amdgcn_s_setprio(0);
      // counted drain: wait B(t+1)+A(t+1) (needed next kg); B(t+2) stays in flight
      asm volatile("s_waitcnt vmcnt(4)" ::: "memory");
      __builtin_amdgcn_s_barrier();
      __builtin_amdgcn_sched_barrier(0);  // publish barrier: next kg reads now
    }
  }

  // drain staging loads before LDS goes away / epilogue
  asm volatile("s_waitcnt vmcnt(0)" ::: "memory");

  if (n0 >= 2560) {
    // v-columns -> vT[b][col-2560][s]; rows are b*2048+s, 4 consecutive s per lane
#pragma unroll
    for (int p = 0; p < 4; ++p)
#pragma unroll
      for (int mi = 0; mi < 2; ++mi) {
        const int row4 = m0 + wm * 128 + p * 32 + mi * 16 + quad * 4;
        const int bb = row4 >> 11, s = row4 & 2047;
#pragma unroll
        for (int ni = 0; ni < 4; ++ni) {
          const int col = n0 + wn * 64 + ni * 16 + l16;
          const float bv = bias[col];
          union { bf16_t h[4]; ushort4 u; } cv;
#pragma unroll
          for (int r = 0; r < 4; ++r) cv.h[r] = __float2bfloat16(acc[p][mi][ni][r] + bv);
          *(ushort4*)&vTp[((size_t)bb * 512 + (col - 2560)) * 2048 + s] = cv.u;
        }
      }
    return;
  }

#pragma unroll
  for (int p = 0; p < 4; ++p)
#pragma unroll
    for (int mi = 0; mi < 2; ++mi) {
      const int row4 = m0 + wm * 128 + p * 32 + mi * 16 + quad * 4;
#pragma unroll
      for (int ni = 0; ni < 4; ++ni) {
        const int col = n0 + wn * 64 + ni * 16 + l16;
        const float bv = bias[col];
#pragma unroll
        for (int r = 0; r < 4; ++r)
          C[(size_t)(row4 + r) * N + col] = __float2bfloat16(acc[p][mi][ni][r] + bv);
      }
    }
}

// ---------------- GQA flash attention (v8: T14 reg-staged prefetch + T5 setprio) ----------------
// Single launch restored (R5 split was instrumentation-only; cost ~+6us).
// Measured R2/R4: 80-81us, MfmaUtil ~41, 4 blocks/CU.
__global__ __launch_bounds__(256, 4) void gqa_attn(
    const bf16_t* __restrict__ QKV, const bf16_t* __restrict__ VT, bf16_t* __restrict__ O,
    int xoff) {
  constexpr int S = 2048, HID = 2048, QKVS = 3072, HD = 64;
  const int tid = threadIdx.x;
  const int w = tid >> 6, lane = tid & 63;
  const int quad = lane >> 4, l16 = lane & 15;
  const int hp = blockIdx.y, b = blockIdx.z;
  const int h = hp * 2 + (w & 1);       // wave's head
  const int g = hp >> 1;                // shared KV group (rep=4: heads 4g..4g+3)
  const int q0 = (xoff + blockIdx.x) * 64 + (w >> 1) * 32;  // wave's 32 q rows

  __shared__ alignas(16) bf16_t Ks[64 * 64];
  __shared__ alignas(16) bf16_t VTs[64 * 64];
  __shared__ alignas(16) bf16_t Ps[128 * 64];

  // Q fragments in registers (B-operand layout: n=l16 -> q, k=quad*8+j); pre-scaled
  bf16x8 qf[2][2];
#pragma unroll
  for (int mt = 0; mt < 2; ++mt)
#pragma unroll
    for (int ks = 0; ks < 2; ++ks)
      qf[mt][ks] = *(const bf16x8*)&QKV[(size_t)(b * S + q0 + mt * 16 + l16) * QKVS +
                                        h * HD + ks * 32 + quad * 8];

  const int rr = lane >> 3, c7 = lane & 7;
  const int sx = l16 & 7;

  const bf16_t* Kbase = QKV + (size_t)b * S * QKVS + 2048 + g * HD;
  const bf16_t* Vbase = VT + (size_t)(b * 512 + g * HD) * S;

  // reg-staging geometry: this thread owns rows srow and srow+8 of the 64-row tile,
  // 16B chunk c7; LDS dest chunk XOR-swizzled with row&7 (= rr).
  const int srow = w * 16 + rr;
  const bf16_t* kp0 = Kbase + (size_t)srow * QKVS + c7 * 8;
  const bf16_t* kp1 = kp0 + (size_t)8 * QKVS;
  const bf16_t* vp0 = Vbase + (size_t)srow * S + c7 * 8;
  const bf16_t* vp1 = vp0 + (size_t)8 * S;
  bf16_t* KsW0 = &Ks[(srow)*64 + (c7 ^ rr) * 8];
  bf16_t* KsW1 = KsW0 + 8 * 64;
  bf16_t* VsW0 = &VTs[(srow)*64 + (c7 ^ rr) * 8];
  bf16_t* VsW1 = VsW0 + 8 * 64;

  f32x4 oacc[2][4] = {};
  f32x4 lacc[2] = {};
  bf16x8 ones;
#pragma unroll
  for (int j = 0; j < 8; ++j) ones[j] = (__bf16)1.0f;

  // prologue: issue tile-0 loads
  uint4 kr0 = *(const uint4*)kp0;
  uint4 kr1 = *(const uint4*)kp1;
  uint4 vr0 = *(const uint4*)vp0;
  uint4 vr1 = *(const uint4*)vp1;

  for (int s0 = 0; s0 < S; s0 += 64) {
    __syncthreads();  // all waves done reading the previous tile's LDS
    *(uint4*)KsW0 = kr0;
    *(uint4*)KsW1 = kr1;
    *(uint4*)VsW0 = vr0;
    *(uint4*)VsW1 = vr1;
    // issue next-tile loads now; they stay in flight across the whole compute phase.
    const int sn = (s0 + 64) & (S - 1);
    kr0 = *(const uint4*)(kp0 + (size_t)sn * QKVS);
    kr1 = *(const uint4*)(kp1 + (size_t)sn * QKVS);
    vr0 = *(const uint4*)(vp0 + sn);
    vr1 = *(const uint4*)(vp1 + sn);
    __syncthreads();  // ds_writes visible to all waves

    __builtin_amdgcn_s_setprio(1);
    // ---- S^T = K·Q^T (row=kv=quad*4+r, col=q=l16); p=exp2(s); pack(trunc) -> Ps[q][kv] ----
#pragma unroll
    for (int nt = 0; nt < 4; ++nt) {
      bf16x8 kf0 = *(const bf16x8*)&Ks[(nt * 16 + l16) * 64 + ((quad ^ sx) * 8)];
      bf16x8 kf1 = *(const bf16x8*)&Ks[(nt * 16 + l16) * 64 + (((4 + quad) ^ sx) * 8)];
#pragma unroll
      for (int mt = 0; mt < 2; ++mt) {
        f32x4 s = {};
        s = MFMA_BF16(kf0, qf[mt][0], s);
        s = MFMA_BF16(kf1, qf[mt][1], s);
        const float p0 = __builtin_amdgcn_exp2f(s[0]);
        const float p1 = __builtin_amdgcn_exp2f(s[1]);
        const float p2 = __builtin_amdgcn_exp2f(s[2]);
        const float p3 = __builtin_amdgcn_exp2f(s[3]);
        uint2 pk;
        pk.x = __builtin_amdgcn_perm(fbits(p1), fbits(p0), 0x07060302);  // [bf16(p1)|bf16(p0)]
        pk.y = __builtin_amdgcn_perm(fbits(p3), fbits(p2), 0x07060302);
        *(uint2*)&Ps[(w * 32 + mt * 16 + l16) * 64 +
                     (((nt * 2 + (quad >> 1)) ^ sx) * 8) + (quad & 1) * 4] = pk;
      }
    }

    // ---- O += P·V; row-sums via ones-B MFMA (sums truncated bf16 P -> bias cancels) ----
#pragma unroll
    for (int kc = 0; kc < 2; ++kc) {
      bf16x8 pf[2];
#pragma unroll
      for (int mt = 0; mt < 2; ++mt) {
        pf[mt] = *(const bf16x8*)&Ps[(w * 32 + mt * 16 + l16) * 64 + (((kc * 4 + quad) ^ sx) * 8)];
        lacc[mt] = MFMA_BF16(pf[mt], ones, lacc[mt]);
      }
#pragma unroll
      for (int dt = 0; dt < 4; ++dt) {
        bf16x8 vf = *(const bf16x8*)&VTs[(dt * 16 + l16) * 64 + (((kc * 4 + quad) ^ sx) * 8)];
#pragma unroll
        for (int mt = 0; mt < 2; ++mt)
          oacc[mt][dt] = MFMA_BF16(pf[mt], vf, oacc[mt][dt]);
      }
    }
    __builtin_amdgcn_s_setprio(0);
  }

  // ---- normalize + store ----
#pragma unroll
  for (int mt = 0; mt < 2; ++mt) {
    float linv[4];
#pragma unroll
    for (int r = 0; r < 4; ++r) linv[r] = 1.0f / lacc[mt][r];
#pragma unroll
    for (int dt = 0; dt < 4; ++dt)
#pragma unroll
      for (int r = 0; r < 4; ++r)
        O[(size_t)(b * S + q0 + mt * 16 + quad * 4 + r) * HID + h * HD + dt * 16 + l16] =
            __float2bfloat16(oacc[mt][dt][r] * linv[r]);
  }
}

extern "C" void kernel_launch(void* const* d_in, const int* in_sizes, int n_in,
                              void* d_out, int out_size, void* d_ws, size_t ws_size,
                              hipStream_t stream) {
  const float* hidden = (const float*)d_in[0];
  const float* Wq = (const float*)d_in[1];
  const float* bq = (const float*)d_in[2];
  const float* Wk = (const float*)d_in[3];
  const float* bk = (const float*)d_in[4];
  const float* Wv = (const float*)d_in[5];
  const float* bv = (const float*)d_in[6];
  const float* Wo = (const float*)d_in[7];
  const float* bo = (const float*)d_in[8];
  float* out = (float*)d_out;

  constexpr int B = 2, S = 2048, HID = 2048, KV = 512, QKVN = 3072;
  constexpr int M = B * S;  // 4096
  const float c1 = 0.125f * 1.44269504089f;

  char* ws = (char*)d_ws;
  bf16_t* hiddenB = (bf16_t*)ws; ws += (size_t)M * HID * 2;
  bf16_t* WqkvT = (bf16_t*)ws;   ws += (size_t)QKVN * HID * 2;
  bf16_t* WoT = (bf16_t*)ws;     ws += (size_t)HID * HID * 2;
  bf16_t* qkv = (bf16_t*)ws;     ws += (size_t)M * QKVN * 2;
  bf16_t* vT = (bf16_t*)ws;      ws += (size_t)M * KV * 2;
  bf16_t* attn = (bf16_t*)ws;    ws += (size_t)M * HID * 2;
  float* bqkv = (float*)ws;      ws += QKVN * 4;

  // one fused prep launch: cast + 4 weight transposes (64x64 tiles) + bias concat
  prep<<<8192 + 2560 + 12, 256, 0, stream>>>(hidden, Wq, Wk, Wv, Wo, bq, bk, bv,
                                             hiddenB, WqkvT, WoT, bqkv, c1);

  // QKV projection: 256^2 mega-phase kernel; v-columns written transposed to vT
  gemm256<<<dim3(QKVN / 256, M / 256), 512, 0, stream>>>(hiddenB, WqkvT, bqkv, qkv, vT);

  // attention: single launch restored (4 blocks/CU)
  gqa_attn<<<dim3(S / 64, 16, B), 256, 0, stream>>>(qkv, vT, attn, 0);

  gemm_bt<float><<<dim3(HID / 128, M / 128), 256, 0, stream>>>(
      attn, WoT, bo, out, (bf16_t*)nullptr, M, HID, HID);
}

// Round 7
// 302.267 us; speedup vs baseline: 1.0350x; 1.0295x over previous
//
#include <hip/hip_runtime.h>
#include <hip/hip_bf16.h>
#include <math.h>

typedef __bf16 bf16x8 __attribute__((ext_vector_type(8)));
typedef float f32x4 __attribute__((ext_vector_type(4)));
typedef __hip_bfloat16 bf16_t;

#define MFMA_BF16(a, b, c) __builtin_amdgcn_mfma_f32_16x16x32_bf16((a), (b), (c), 0, 0, 0)

// async global->LDS, 16B per lane; LDS dest = wave-uniform base + lane*16
__device__ __forceinline__ void async_copy16(const bf16_t* g, bf16_t* lds_base) {
  __builtin_amdgcn_global_load_lds(
      (const __attribute__((address_space(1))) unsigned int*)g,
      (__attribute__((address_space(3))) unsigned int*)lds_base,
      16, 0, 0);
}

__device__ __forceinline__ unsigned fbits(float x) { return __builtin_bit_cast(unsigned, x); }

// ---------------- fused prep: cast hidden, transpose 4 weights, concat bias ----------------
__global__ __launch_bounds__(256) void prep(
    const float* __restrict__ hidden, const float* __restrict__ Wq, const float* __restrict__ Wk,
    const float* __restrict__ Wv, const float* __restrict__ Wo,
    const float* __restrict__ bq, const float* __restrict__ bk, const float* __restrict__ bv,
    bf16_t* __restrict__ hiddenB, bf16_t* __restrict__ WqkvT, bf16_t* __restrict__ WoT,
    float* __restrict__ bqkv, float c1) {
  __shared__ float tile[64][65];
  int bid = blockIdx.x;
  const int t = threadIdx.x;
  if (bid < 8192) {  // cast hidden f32 -> bf16, float4 per thread
    const int i = bid * 256 + t;
    float4 v = ((const float4*)hidden)[i];
    union { bf16_t h[4]; ushort4 u; } cv;
    cv.h[0] = __float2bfloat16(v.x);
    cv.h[1] = __float2bfloat16(v.y);
    cv.h[2] = __float2bfloat16(v.z);
    cv.h[3] = __float2bfloat16(v.w);
    ((ushort4*)hiddenB)[i] = cv.u;
    return;
  }
  bid -= 8192;
  if (bid >= 2560) {  // bias concat: 12 blocks x 256 = 3072
    const int i = (bid - 2560) * 256 + t;
    float v;
    if (i < 2048) v = bq[i] * c1;
    else if (i < 2560) v = bk[i - 2048];
    else v = bv[i - 2560];
    bqkv[i] = v;
    return;
  }
  // weight transpose: in [2048][C] -> out [C][2048], 64x64 tiles
  const float* src;
  bf16_t* dst;
  int Cc, bx, by;
  float scale = 1.0f;
  if (bid < 1024) { src = Wq; dst = WqkvT; Cc = 2048; bx = bid & 31; by = bid >> 5; scale = c1; }
  else if (bid < 1280) { bid -= 1024; src = Wk; dst = WqkvT + (size_t)2048 * 2048; Cc = 512; bx = bid & 7; by = bid >> 3; }
  else if (bid < 1536) { bid -= 1280; src = Wv; dst = WqkvT + (size_t)2560 * 2048; Cc = 512; bx = bid & 7; by = bid >> 3; }
  else { bid -= 1536; src = Wo; dst = WoT; Cc = 2048; bx = bid & 31; by = bid >> 5; }
  const int tx = t & 63, ty = t >> 6;
  const int c0 = bx * 64, r0 = by * 64;
#pragma unroll
  for (int i = ty; i < 64; i += 4)
    tile[i][tx] = src[(size_t)(r0 + i) * Cc + c0 + tx];
  __syncthreads();
#pragma unroll
  for (int i = ty; i < 64; i += 4)
    dst[(size_t)(c0 + i) * 2048 + r0 + tx] = __float2bfloat16(tile[tx][i] * scale);
}

// ---------------- GEMM v7 (128^2, 2-barrier): kept for gemm2 ----------------
template <typename TOUT>
__global__ __launch_bounds__(256, 3) void gemm_bt(
    const bf16_t* __restrict__ A, const bf16_t* __restrict__ Bt,
    const float* __restrict__ bias, TOUT* __restrict__ C, bf16_t* __restrict__ vTp,
    int M, int N, int K) {
  __shared__ alignas(16) bf16_t As[128 * 64];
  __shared__ alignas(16) bf16_t Bs[128 * 64];

  const int tid = threadIdx.x;
  const int w = tid >> 6, lane = tid & 63;
  const int quad = lane >> 4, l16 = lane & 15;
  const int wm = w >> 1, wn = w & 1;
  const int m0 = blockIdx.y * 128, n0 = blockIdx.x * 128;

  f32x4 acc[4][4] = {};

  const int rr = lane >> 3;                 // row within 8-row staging chunk
  const int scol = ((lane & 7) ^ rr) * 8;   // swizzled SOURCE col (bf16 units)
  const int sx = l16 & 7;                   // row&7 for fragment reads

  for (int k0 = 0; k0 < K; k0 += 64) {
    __syncthreads();
#pragma unroll
    for (int c = 0; c < 4; ++c) {
      const int r = w * 32 + c * 8 + rr;
      async_copy16(A + (size_t)(m0 + r) * K + k0 + scol, &As[(w * 32 + c * 8) * 64]);
      async_copy16(Bt + (size_t)(n0 + r) * K + k0 + scol, &Bs[(w * 32 + c * 8) * 64]);
    }
    __syncthreads();

#pragma unroll
    for (int kh = 0; kh < 2; ++kh) {
      bf16x8 af[4], bf[4];
#pragma unroll
      for (int i = 0; i < 4; ++i) {
        af[i] = *(const bf16x8*)&As[(wm * 64 + i * 16 + l16) * 64 + (((kh * 4 + quad) ^ sx) * 8)];
        bf[i] = *(const bf16x8*)&Bs[(wn * 64 + i * 16 + l16) * 64 + (((kh * 4 + quad) ^ sx) * 8)];
      }
#pragma unroll
      for (int i = 0; i < 4; ++i)
#pragma unroll
        for (int j = 0; j < 4; ++j)
          acc[i][j] = MFMA_BF16(af[i], bf[j], acc[i][j]);
    }
  }

  if (vTp != nullptr && n0 >= 2560) {
#pragma unroll
    for (int i = 0; i < 4; ++i) {
      const int row = m0 + wm * 64 + i * 16 + quad * 4;
      const int bb = row >> 11, s = row & 2047;
#pragma unroll
      for (int j = 0; j < 4; ++j) {
        const int col = n0 + wn * 64 + j * 16 + l16;
        const float bv = bias[col];
        union { bf16_t h[4]; ushort4 u; } cv;
#pragma unroll
        for (int r = 0; r < 4; ++r) cv.h[r] = __float2bfloat16(acc[i][j][r] + bv);
        *(ushort4*)&vTp[((size_t)bb * 512 + (col - 2560)) * 2048 + s] = cv.u;
      }
    }
    return;
  }

#pragma unroll
  for (int i = 0; i < 4; ++i) {
    const int row = m0 + wm * 64 + i * 16 + quad * 4;
#pragma unroll
    for (int j = 0; j < 4; ++j) {
      const int col = n0 + wn * 64 + j * 16 + l16;
      const float bv = bias[col];
#pragma unroll
      for (int r = 0; r < 4; ++r) {
        const float val = acc[i][j][r] + bv;
        if constexpr (__is_same(TOUT, float)) {
          C[(size_t)(row + r) * N + col] = val;
        } else {
          C[(size_t)(row + r) * N + col] = __float2bfloat16(val);
        }
      }
    }
  }
}

// ---------------- GEMM v9.3: 256^2, 2 mega-phases per K-tile (kept; dropped below attn in R6) ----------------
__global__ __launch_bounds__(512, 2) void gemm256(
    const bf16_t* __restrict__ A, const bf16_t* __restrict__ Bt,
    const float* __restrict__ bias, bf16_t* __restrict__ C, bf16_t* __restrict__ vTp) {
  constexpr int N = 3072, K = 2048;
  __shared__ alignas(16) bf16_t As[2 * 256 * 64];
  __shared__ alignas(16) bf16_t Bs[2 * 256 * 64];

  const int tid = threadIdx.x;
  const int w = tid >> 6, lane = tid & 63;
  const int quad = lane >> 4, l16 = lane & 15;
  const int wm = w >> 2, wn = w & 3;

  // T1: XCD-aware swizzle. flat = y*12+x; swz = (flat%8)*24 + flat/8 (bijective, 192%8==0)
  const int flat = blockIdx.y * 12 + blockIdx.x;
  const int swz = (flat & 7) * 24 + (flat >> 3);
  const int m0 = (swz / 12) * 256, n0 = (swz % 12) * 256;

  const int rr = lane >> 3, c7 = lane & 7;
  const int scol = (c7 ^ rr) * 8;  // inverse-swizzled SOURCE col (bf16 units)
  const int sx = l16 & 7;          // row&7 for fragment reads

  // stage one 128-row half-tile (2 x global_load_lds per wave)
  auto stA = [&](int t, int h) {
    const int kb = (t & 31) * 64;
    const int rbase = h * 128 + w * 8;
    bf16_t* d0 = &As[(t & 1) * (256 * 64) + rbase * 64];
    const bf16_t* s0 = A + (size_t)(m0 + rbase + rr) * K + kb + scol;
    async_copy16(s0, d0);
    async_copy16(s0 + (size_t)64 * K, d0 + 64 * 64);
  };
  auto stB = [&](int t, int h) {
    const int kb = (t & 31) * 64;
    const int rbase = h * 128 + w * 8;
    bf16_t* d0 = &Bs[(t & 1) * (256 * 64) + rbase * 64];
    const bf16_t* s0 = Bt + (size_t)(n0 + rbase + rr) * K + kb + scol;
    async_copy16(s0, d0);
    async_copy16(s0 + (size_t)64 * K, d0 + 64 * 64);
  };

  f32x4 acc[4][2][4] = {};  // [quadrant][mi][ni]

  // prologue: tile0 fully staged, tile1.B in flight (newest 4 loads) -> vmcnt(4)
  stB(0, 0); stB(0, 1); stA(0, 0); stA(0, 1);
  stB(1, 0); stB(1, 1);
  asm volatile("s_waitcnt vmcnt(4)" ::: "memory");
  __builtin_amdgcn_s_barrier();
  __builtin_amdgcn_sched_barrier(0);  // publish barrier: tile0 read immediately below

  for (int it = 0; it < 16; ++it) {
#pragma unroll
    for (int kg = 0; kg < 2; ++kg) {
      const int t = it * 2 + kg;
      const int ta = (t + 1) & 31;  // stA target tile
      const int tb = (t + 2) & 31;  // stB target tile
      const bf16_t* Asb = &As[(t & 1) * (256 * 64)];
      const bf16_t* Bsb = &Bs[(t & 1) * (256 * 64)];

      // ---- mega-phase 0: B + A-quadrants 0,1 ; stage A(t+1) ----
      bf16x8 b[4][2];
#pragma unroll
      for (int ni = 0; ni < 4; ++ni)
#pragma unroll
        for (int kk = 0; kk < 2; ++kk)
          b[ni][kk] = *(const bf16x8*)&Bsb[(wn * 64 + ni * 16 + l16) * 64 +
                                           (((kk * 4 + quad) ^ sx) * 8)];
      bf16x8 a01[2][2][2];
#pragma unroll
      for (int p = 0; p < 2; ++p)
#pragma unroll
        for (int mi = 0; mi < 2; ++mi)
#pragma unroll
          for (int kk = 0; kk < 2; ++kk)
            a01[p][mi][kk] = *(const bf16x8*)&Asb[(wm * 128 + p * 32 + mi * 16 + l16) * 64 +
                                                  (((kk * 4 + quad) ^ sx) * 8)];
      stA(ta, 0); stA(ta, 1);
      __builtin_amdgcn_s_barrier();
      __builtin_amdgcn_s_setprio(1);
#pragma unroll
      for (int p = 0; p < 2; ++p)
#pragma unroll
        for (int kk = 0; kk < 2; ++kk)
#pragma unroll
          for (int mi = 0; mi < 2; ++mi)
#pragma unroll
            for (int ni = 0; ni < 4; ++ni)
              acc[p][mi][ni] = MFMA_BF16(a01[p][mi][kk], b[ni][kk], acc[p][mi][ni]);
      __builtin_amdgcn_s_setprio(0);
      __builtin_amdgcn_s_barrier();

      // ---- mega-phase 1: A-quadrants 2,3 ; stage B(t+2) ; drain ----
      bf16x8 a23[2][2][2];
#pragma unroll
      for (int p = 0; p < 2; ++p)
#pragma unroll
        for (int mi = 0; mi < 2; ++mi)
#pragma unroll
          for (int kk = 0; kk < 2; ++kk)
            a23[p][mi][kk] = *(const bf16x8*)&Asb[(wm * 128 + (p + 2) * 32 + mi * 16 + l16) * 64 +
                                                  (((kk * 4 + quad) ^ sx) * 8)];
      stB(tb, 0); stB(tb, 1);
      __builtin_amdgcn_s_barrier();
      __builtin_amdgcn_s_setprio(1);
#pragma unroll
      for (int p = 0; p < 2; ++p)
#pragma unroll
        for (int kk = 0; kk < 2; ++kk)
#pragma unroll
          for (int mi = 0; mi < 2; ++mi)
#pragma unroll
            for (int ni = 0; ni < 4; ++ni)
              acc[p + 2][mi][ni] = MFMA_BF16(a23[p][mi][kk], b[ni][kk], acc[p + 2][mi][ni]);
      __builtin_amdgcn_s_setprio(0);
      // counted drain: wait B(t+1)+A(t+1) (needed next kg); B(t+2) stays in flight
      asm volatile("s_waitcnt vmcnt(4)" ::: "memory");
      __builtin_amdgcn_s_barrier();
      __builtin_amdgcn_sched_barrier(0);  // publish barrier: next kg reads now
    }
  }

  // drain staging loads before LDS goes away / epilogue
  asm volatile("s_waitcnt vmcnt(0)" ::: "memory");

  if (n0 >= 2560) {
    // v-columns -> vT[b][col-2560][s]; rows are b*2048+s, 4 consecutive s per lane
#pragma unroll
    for (int p = 0; p < 4; ++p)
#pragma unroll
      for (int mi = 0; mi < 2; ++mi) {
        const int row4 = m0 + wm * 128 + p * 32 + mi * 16 + quad * 4;
        const int bb = row4 >> 11, s = row4 & 2047;
#pragma unroll
        for (int ni = 0; ni < 4; ++ni) {
          const int col = n0 + wn * 64 + ni * 16 + l16;
          const float bv = bias[col];
          union { bf16_t h[4]; ushort4 u; } cv;
#pragma unroll
          for (int r = 0; r < 4; ++r) cv.h[r] = __float2bfloat16(acc[p][mi][ni][r] + bv);
          *(ushort4*)&vTp[((size_t)bb * 512 + (col - 2560)) * 2048 + s] = cv.u;
        }
      }
    return;
  }

#pragma unroll
  for (int p = 0; p < 4; ++p)
#pragma unroll
    for (int mi = 0; mi < 2; ++mi) {
      const int row4 = m0 + wm * 128 + p * 32 + mi * 16 + quad * 4;
#pragma unroll
      for (int ni = 0; ni < 4; ++ni) {
        const int col = n0 + wn * 64 + ni * 16 + l16;
        const float bv = bias[col];
#pragma unroll
        for (int r = 0; r < 4; ++r)
          C[(size_t)(row4 + r) * N + col] = __float2bfloat16(acc[p][mi][ni][r] + bv);
      }
    }
}

// ---------------- GQA flash attention v9: 4-head KV sharing + LDS double-buffer ----------------
// Block = 64 q-rows x 4 heads (one full KV group g = blockIdx.y), 8 waves/512 thr.
// Wave w: head g*4+(w&3), q-rows q0 = bx*64+(w>>2)*32 — per-wave MFMA/softmax math is
// byte-identical to v8; only staging geometry, head mapping, and Ps size change.
// v9 changes vs v8 (R6: 78.2us, MfmaUtil 42, ~20% idle = barrier+staging overhead):
//  * K/V tile staged once per 4 heads (was 2): 1 K-load + 1 V-load per wave (was 2+2).
//  * double-buffered Ks/VTs -> ONE __syncthreads per iter (was 2; 32 barriers vs 64).
//    Race-free: iter t writes buf[t&1]; its readers ran at iter t-2 before bar(t-1),
//    so passing bar(t-1) implies those reads completed. T14 reg-prefetch unchanged.
//  * LDS 64KB (2x8K K + 2x8K V + 32K Ps[256][64]) -> 2 blocks/CU, 16 waves/CU (same).
__global__ __launch_bounds__(512, 2) void gqa_attn(
    const bf16_t* __restrict__ QKV, const bf16_t* __restrict__ VT, bf16_t* __restrict__ O) {
  constexpr int S = 2048, HID = 2048, QKVS = 3072, HD = 64;
  const int tid = threadIdx.x;
  const int w = tid >> 6, lane = tid & 63;
  const int quad = lane >> 4, l16 = lane & 15;
  const int g = blockIdx.y, b = blockIdx.z;
  const int h = g * 4 + (w & 3);                   // wave's head (rep=4 GQA mapping)
  const int q0 = blockIdx.x * 64 + (w >> 2) * 32;  // wave's 32 q rows

  __shared__ alignas(16) bf16_t Ks[2 * 64 * 64];
  __shared__ alignas(16) bf16_t VTs[2 * 64 * 64];
  __shared__ alignas(16) bf16_t Ps[256 * 64];

  // Q fragments in registers (B-operand layout: n=l16 -> q, k=quad*8+j); pre-scaled
  bf16x8 qf[2][2];
#pragma unroll
  for (int mt = 0; mt < 2; ++mt)
#pragma unroll
    for (int ks = 0; ks < 2; ++ks)
      qf[mt][ks] = *(const bf16x8*)&QKV[(size_t)(b * S + q0 + mt * 16 + l16) * QKVS +
                                        h * HD + ks * 32 + quad * 8];

  const int rr = lane >> 3, c7 = lane & 7;
  const int sx = l16 & 7;

  const bf16_t* Kbase = QKV + (size_t)b * S * QKVS + 2048 + g * HD;
  const bf16_t* Vbase = VT + (size_t)(b * 512 + g * HD) * S;

  // staging: 8 waves x 8 rows — thread owns row srow = w*8+rr, 16B chunk c7.
  // LDS dest chunk XOR-swizzled with row&7 (= rr); read side uses l16&7 (= sx): consistent.
  const int srow = w * 8 + rr;
  const bf16_t* kp = Kbase + (size_t)srow * QKVS + c7 * 8;
  const bf16_t* vp = Vbase + (size_t)srow * S + c7 * 8;
  const int woff = srow * 64 + (c7 ^ rr) * 8;  // within-buffer LDS write offset

  f32x4 oacc[2][4] = {};
  f32x4 lacc[2] = {};
  bf16x8 ones;
#pragma unroll
  for (int j = 0; j < 8; ++j) ones[j] = (__bf16)1.0f;

  // prologue: tile 0 -> regs
  uint4 kr = *(const uint4*)kp;
  uint4 vr = *(const uint4*)vp;

  for (int it = 0; it < 32; ++it) {
    const int cur = (it & 1) * (64 * 64);
    // write tile `it`; prefetch tile it+1 (wraps harmlessly on last iter)
    *(uint4*)&Ks[cur + woff] = kr;
    *(uint4*)&VTs[cur + woff] = vr;
    const int sn = ((it + 1) & 31) * 64;
    kr = *(const uint4*)(kp + (size_t)sn * QKVS);
    vr = *(const uint4*)(vp + sn);
    __syncthreads();  // tile `it` visible; all reads of buf[(it+1)&1] (iter it-1) done

    __builtin_amdgcn_s_setprio(1);
    // ---- S^T = K·Q^T (row=kv=quad*4+r, col=q=l16); p=exp2(s); pack(trunc) -> Ps[q][kv] ----
#pragma unroll
    for (int nt = 0; nt < 4; ++nt) {
      bf16x8 kf0 = *(const bf16x8*)&Ks[cur + (nt * 16 + l16) * 64 + ((quad ^ sx) * 8)];
      bf16x8 kf1 = *(const bf16x8*)&Ks[cur + (nt * 16 + l16) * 64 + (((4 + quad) ^ sx) * 8)];
#pragma unroll
      for (int mt = 0; mt < 2; ++mt) {
        f32x4 s = {};
        s = MFMA_BF16(kf0, qf[mt][0], s);
        s = MFMA_BF16(kf1, qf[mt][1], s);
        const float p0 = __builtin_amdgcn_exp2f(s[0]);
        const float p1 = __builtin_amdgcn_exp2f(s[1]);
        const float p2 = __builtin_amdgcn_exp2f(s[2]);
        const float p3 = __builtin_amdgcn_exp2f(s[3]);
        uint2 pk;
        pk.x = __builtin_amdgcn_perm(fbits(p1), fbits(p0), 0x07060302);  // [bf16(p1)|bf16(p0)]
        pk.y = __builtin_amdgcn_perm(fbits(p3), fbits(p2), 0x07060302);
        *(uint2*)&Ps[(w * 32 + mt * 16 + l16) * 64 +
                     (((nt * 2 + (quad >> 1)) ^ sx) * 8) + (quad & 1) * 4] = pk;
      }
    }

    // ---- O += P·V; row-sums via ones-B MFMA (sums truncated bf16 P -> bias cancels) ----
#pragma unroll
    for (int kc = 0; kc < 2; ++kc) {
      bf16x8 pf[2];
#pragma unroll
      for (int mt = 0; mt < 2; ++mt) {
        pf[mt] = *(const bf16x8*)&Ps[(w * 32 + mt * 16 + l16) * 64 + (((kc * 4 + quad) ^ sx) * 8)];
        lacc[mt] = MFMA_BF16(pf[mt], ones, lacc[mt]);
      }
#pragma unroll
      for (int dt = 0; dt < 4; ++dt) {
        bf16x8 vf = *(const bf16x8*)&VTs[cur + (dt * 16 + l16) * 64 + (((kc * 4 + quad) ^ sx) * 8)];
#pragma unroll
        for (int mt = 0; mt < 2; ++mt)
          oacc[mt][dt] = MFMA_BF16(pf[mt], vf, oacc[mt][dt]);
      }
    }
    __builtin_amdgcn_s_setprio(0);
  }

  // ---- normalize + store ----
#pragma unroll
  for (int mt = 0; mt < 2; ++mt) {
    float linv[4];
#pragma unroll
    for (int r = 0; r < 4; ++r) linv[r] = 1.0f / lacc[mt][r];
#pragma unroll
    for (int dt = 0; dt < 4; ++dt)
#pragma unroll
      for (int r = 0; r < 4; ++r)
        O[(size_t)(b * S + q0 + mt * 16 + quad * 4 + r) * HID + h * HD + dt * 16 + l16] =
            __float2bfloat16(oacc[mt][dt][r] * linv[r]);
  }
}

extern "C" void kernel_launch(void* const* d_in, const int* in_sizes, int n_in,
                              void* d_out, int out_size, void* d_ws, size_t ws_size,
                              hipStream_t stream) {
  const float* hidden = (const float*)d_in[0];
  const float* Wq = (const float*)d_in[1];
  const float* bq = (const float*)d_in[2];
  const float* Wk = (const float*)d_in[3];
  const float* bk = (const float*)d_in[4];
  const float* Wv = (const float*)d_in[5];
  const float* bv = (const float*)d_in[6];
  const float* Wo = (const float*)d_in[7];
  const float* bo = (const float*)d_in[8];
  float* out = (float*)d_out;

  constexpr int B = 2, S = 2048, HID = 2048, KV = 512, QKVN = 3072;
  constexpr int M = B * S;  // 4096
  const float c1 = 0.125f * 1.44269504089f;

  char* ws = (char*)d_ws;
  bf16_t* hiddenB = (bf16_t*)ws; ws += (size_t)M * HID * 2;
  bf16_t* WqkvT = (bf16_t*)ws;   ws += (size_t)QKVN * HID * 2;
  bf16_t* WoT = (bf16_t*)ws;     ws += (size_t)HID * HID * 2;
  bf16_t* qkv = (bf16_t*)ws;     ws += (size_t)M * QKVN * 2;
  bf16_t* vT = (bf16_t*)ws;      ws += (size_t)M * KV * 2;
  bf16_t* attn = (bf16_t*)ws;    ws += (size_t)M * HID * 2;
  float* bqkv = (float*)ws;      ws += QKVN * 4;

  // one fused prep launch: cast + 4 weight transposes (64x64 tiles) + bias concat
  prep<<<8192 + 2560 + 12, 256, 0, stream>>>(hidden, Wq, Wk, Wv, Wo, bq, bk, bv,
                                             hiddenB, WqkvT, WoT, bqkv, c1);

  // QKV projection: 256^2 mega-phase kernel; v-columns written transposed to vT
  gemm256<<<dim3(QKVN / 256, M / 256), 512, 0, stream>>>(hiddenB, WqkvT, bqkv, qkv, vT);

  // attention v9: 512 blocks (32 q-blocks x 8 KV-groups x B), 8 waves each
  gqa_attn<<<dim3(S / 64, 8, B), 512, 0, stream>>>(qkv, vT, attn);

  gemm_bt<float><<<dim3(HID / 128, M / 128), 256, 0, stream>>>(
      attn, WoT, bo, out, (bf16_t*)nullptr, M, HID, HID);
}

// Round 8
// 300.043 us; speedup vs baseline: 1.0427x; 1.0074x over previous
//
#include <hip/hip_runtime.h>
#include <hip/hip_bf16.h>
#include <math.h>

typedef __bf16 bf16x8 __attribute__((ext_vector_type(8)));
typedef float f32x4 __attribute__((ext_vector_type(4)));
typedef __hip_bfloat16 bf16_t;

#define MFMA_BF16(a, b, c) __builtin_amdgcn_mfma_f32_16x16x32_bf16((a), (b), (c), 0, 0, 0)

// async global->LDS, 16B per lane; LDS dest = wave-uniform base + lane*16
__device__ __forceinline__ void async_copy16(const bf16_t* g, bf16_t* lds_base) {
  __builtin_amdgcn_global_load_lds(
      (const __attribute__((address_space(1))) unsigned int*)g,
      (__attribute__((address_space(3))) unsigned int*)lds_base,
      16, 0, 0);
}

__device__ __forceinline__ unsigned fbits(float x) { return __builtin_bit_cast(unsigned, x); }

// ---------------- fused prep: cast hidden, transpose 4 weights, concat bias ----------------
__global__ __launch_bounds__(256) void prep(
    const float* __restrict__ hidden, const float* __restrict__ Wq, const float* __restrict__ Wk,
    const float* __restrict__ Wv, const float* __restrict__ Wo,
    const float* __restrict__ bq, const float* __restrict__ bk, const float* __restrict__ bv,
    bf16_t* __restrict__ hiddenB, bf16_t* __restrict__ WqkvT, bf16_t* __restrict__ WoT,
    float* __restrict__ bqkv, float c1) {
  __shared__ float tile[64][65];
  int bid = blockIdx.x;
  const int t = threadIdx.x;
  if (bid < 8192) {  // cast hidden f32 -> bf16, float4 per thread
    const int i = bid * 256 + t;
    float4 v = ((const float4*)hidden)[i];
    union { bf16_t h[4]; ushort4 u; } cv;
    cv.h[0] = __float2bfloat16(v.x);
    cv.h[1] = __float2bfloat16(v.y);
    cv.h[2] = __float2bfloat16(v.z);
    cv.h[3] = __float2bfloat16(v.w);
    ((ushort4*)hiddenB)[i] = cv.u;
    return;
  }
  bid -= 8192;
  if (bid >= 2560) {  // bias concat: 12 blocks x 256 = 3072
    const int i = (bid - 2560) * 256 + t;
    float v;
    if (i < 2048) v = bq[i] * c1;
    else if (i < 2560) v = bk[i - 2048];
    else v = bv[i - 2560];
    bqkv[i] = v;
    return;
  }
  // weight transpose: in [2048][C] -> out [C][2048], 64x64 tiles
  const float* src;
  bf16_t* dst;
  int Cc, bx, by;
  float scale = 1.0f;
  if (bid < 1024) { src = Wq; dst = WqkvT; Cc = 2048; bx = bid & 31; by = bid >> 5; scale = c1; }
  else if (bid < 1280) { bid -= 1024; src = Wk; dst = WqkvT + (size_t)2048 * 2048; Cc = 512; bx = bid & 7; by = bid >> 3; }
  else if (bid < 1536) { bid -= 1280; src = Wv; dst = WqkvT + (size_t)2560 * 2048; Cc = 512; bx = bid & 7; by = bid >> 3; }
  else { bid -= 1536; src = Wo; dst = WoT; Cc = 2048; bx = bid & 31; by = bid >> 5; }
  const int tx = t & 63, ty = t >> 6;
  const int c0 = bx * 64, r0 = by * 64;
#pragma unroll
  for (int i = ty; i < 64; i += 4)
    tile[i][tx] = src[(size_t)(r0 + i) * Cc + c0 + tx];
  __syncthreads();
#pragma unroll
  for (int i = ty; i < 64; i += 4)
    dst[(size_t)(c0 + i) * 2048 + r0 + tx] = __float2bfloat16(tile[tx][i] * scale);
}

// ---------------- GEMM v7.1 (128^2, 2-barrier, 3 blocks/CU) + T1 XCD swizzle ----------------
// R7 post-mortem: the 256^2 1-block/CU gemm256 (all 3 schedule variants, 68.9-81.2us,
// MfmaUtil 25-29, 60%+ no-issue cycles) loses to this kernel's cross-block latency hiding
// (12 waves/CU from 3 independent blocks). Reverted gemm1 to this proven structure.
// v7.1 adds bijective XCD-aware block swizzle (T1): both call-site grids (768, 512 blocks)
// are %8==0, so swz=(flat%8)*(nwg/8)+flat/8 is bijective; each XCD gets a contiguous tile
// range -> A-panel reuse lands in its private L2.
template <typename TOUT>
__global__ __launch_bounds__(256, 3) void gemm_bt(
    const bf16_t* __restrict__ A, const bf16_t* __restrict__ Bt,
    const float* __restrict__ bias, TOUT* __restrict__ C, bf16_t* __restrict__ vTp,
    int M, int N, int K) {
  __shared__ alignas(16) bf16_t As[128 * 64];
  __shared__ alignas(16) bf16_t Bs[128 * 64];

  const int tid = threadIdx.x;
  const int w = tid >> 6, lane = tid & 63;
  const int quad = lane >> 4, l16 = lane & 15;
  const int wm = w >> 1, wn = w & 1;

  // T1 bijective XCD swizzle (requires nwg % 8 == 0 — true for both call sites)
  const int nwg = gridDim.x * gridDim.y;
  const int flat = blockIdx.y * gridDim.x + blockIdx.x;
  const int swz = (flat & 7) * (nwg >> 3) + (flat >> 3);
  const int m0 = (swz / gridDim.x) * 128, n0 = (swz % gridDim.x) * 128;

  f32x4 acc[4][4] = {};

  const int rr = lane >> 3;                 // row within 8-row staging chunk
  const int scol = ((lane & 7) ^ rr) * 8;   // swizzled SOURCE col (bf16 units)
  const int sx = l16 & 7;                   // row&7 for fragment reads

  for (int k0 = 0; k0 < K; k0 += 64) {
    __syncthreads();
#pragma unroll
    for (int c = 0; c < 4; ++c) {
      const int r = w * 32 + c * 8 + rr;
      async_copy16(A + (size_t)(m0 + r) * K + k0 + scol, &As[(w * 32 + c * 8) * 64]);
      async_copy16(Bt + (size_t)(n0 + r) * K + k0 + scol, &Bs[(w * 32 + c * 8) * 64]);
    }
    __syncthreads();

#pragma unroll
    for (int kh = 0; kh < 2; ++kh) {
      bf16x8 af[4], bf[4];
#pragma unroll
      for (int i = 0; i < 4; ++i) {
        af[i] = *(const bf16x8*)&As[(wm * 64 + i * 16 + l16) * 64 + (((kh * 4 + quad) ^ sx) * 8)];
        bf[i] = *(const bf16x8*)&Bs[(wn * 64 + i * 16 + l16) * 64 + (((kh * 4 + quad) ^ sx) * 8)];
      }
#pragma unroll
      for (int i = 0; i < 4; ++i)
#pragma unroll
        for (int j = 0; j < 4; ++j)
          acc[i][j] = MFMA_BF16(af[i], bf[j], acc[i][j]);
    }
  }

  if (vTp != nullptr && n0 >= 2560) {
    // v-columns -> vT[b][col-2560][s]; rows here are b*2048+s with 4 consecutive s per lane
#pragma unroll
    for (int i = 0; i < 4; ++i) {
      const int row = m0 + wm * 64 + i * 16 + quad * 4;
      const int bb = row >> 11, s = row & 2047;
#pragma unroll
      for (int j = 0; j < 4; ++j) {
        const int col = n0 + wn * 64 + j * 16 + l16;
        const float bv = bias[col];
        union { bf16_t h[4]; ushort4 u; } cv;
#pragma unroll
        for (int r = 0; r < 4; ++r) cv.h[r] = __float2bfloat16(acc[i][j][r] + bv);
        *(ushort4*)&vTp[((size_t)bb * 512 + (col - 2560)) * 2048 + s] = cv.u;
      }
    }
    return;
  }

#pragma unroll
  for (int i = 0; i < 4; ++i) {
    const int row = m0 + wm * 64 + i * 16 + quad * 4;
#pragma unroll
    for (int j = 0; j < 4; ++j) {
      const int col = n0 + wn * 64 + j * 16 + l16;
      const float bv = bias[col];
#pragma unroll
      for (int r = 0; r < 4; ++r) {
        const float val = acc[i][j][r] + bv;
        if constexpr (__is_same(TOUT, float)) {
          C[(size_t)(row + r) * N + col] = val;
        } else {
          C[(size_t)(row + r) * N + col] = __float2bfloat16(val);
        }
      }
    }
  }
}

// ---------------- GQA flash attention v9: 4-head KV sharing + LDS double-buffer ----------------
// Block = 64 q-rows x 4 heads (one full KV group g = blockIdx.y), 8 waves/512 thr.
// Wave w: head g*4+(w&3), q-rows q0 = bx*64+(w>>2)*32 — per-wave MFMA/softmax math is
// byte-identical to v8. K/V staged once per 4 heads; double-buffered -> 1 barrier/iter.
// R7: dropped out of top-5 (<= 81us, was 78.2 argmax in R6) — win, kept unchanged.
__global__ __launch_bounds__(512, 2) void gqa_attn(
    const bf16_t* __restrict__ QKV, const bf16_t* __restrict__ VT, bf16_t* __restrict__ O) {
  constexpr int S = 2048, HID = 2048, QKVS = 3072, HD = 64;
  const int tid = threadIdx.x;
  const int w = tid >> 6, lane = tid & 63;
  const int quad = lane >> 4, l16 = lane & 15;
  const int g = blockIdx.y, b = blockIdx.z;
  const int h = g * 4 + (w & 3);                   // wave's head (rep=4 GQA mapping)
  const int q0 = blockIdx.x * 64 + (w >> 2) * 32;  // wave's 32 q rows

  __shared__ alignas(16) bf16_t Ks[2 * 64 * 64];
  __shared__ alignas(16) bf16_t VTs[2 * 64 * 64];
  __shared__ alignas(16) bf16_t Ps[256 * 64];

  // Q fragments in registers (B-operand layout: n=l16 -> q, k=quad*8+j); pre-scaled
  bf16x8 qf[2][2];
#pragma unroll
  for (int mt = 0; mt < 2; ++mt)
#pragma unroll
    for (int ks = 0; ks < 2; ++ks)
      qf[mt][ks] = *(const bf16x8*)&QKV[(size_t)(b * S + q0 + mt * 16 + l16) * QKVS +
                                        h * HD + ks * 32 + quad * 8];

  const int rr = lane >> 3, c7 = lane & 7;
  const int sx = l16 & 7;

  const bf16_t* Kbase = QKV + (size_t)b * S * QKVS + 2048 + g * HD;
  const bf16_t* Vbase = VT + (size_t)(b * 512 + g * HD) * S;

  // staging: 8 waves x 8 rows — thread owns row srow = w*8+rr, 16B chunk c7.
  // LDS dest chunk XOR-swizzled with row&7 (= rr); read side uses l16&7 (= sx): consistent.
  const int srow = w * 8 + rr;
  const bf16_t* kp = Kbase + (size_t)srow * QKVS + c7 * 8;
  const bf16_t* vp = Vbase + (size_t)srow * S + c7 * 8;
  const int woff = srow * 64 + (c7 ^ rr) * 8;  // within-buffer LDS write offset

  f32x4 oacc[2][4] = {};
  f32x4 lacc[2] = {};
  bf16x8 ones;
#pragma unroll
  for (int j = 0; j < 8; ++j) ones[j] = (__bf16)1.0f;

  // prologue: tile 0 -> regs
  uint4 kr = *(const uint4*)kp;
  uint4 vr = *(const uint4*)vp;

  for (int it = 0; it < 32; ++it) {
    const int cur = (it & 1) * (64 * 64);
    // write tile `it`; prefetch tile it+1 (wraps harmlessly on last iter)
    *(uint4*)&Ks[cur + woff] = kr;
    *(uint4*)&VTs[cur + woff] = vr;
    const int sn = ((it + 1) & 31) * 64;
    kr = *(const uint4*)(kp + (size_t)sn * QKVS);
    vr = *(const uint4*)(vp + sn);
    __syncthreads();  // tile `it` visible; all reads of buf[(it+1)&1] (iter it-1) done

    __builtin_amdgcn_s_setprio(1);
    // ---- S^T = K·Q^T (row=kv=quad*4+r, col=q=l16); p=exp2(s); pack(trunc) -> Ps[q][kv] ----
#pragma unroll
    for (int nt = 0; nt < 4; ++nt) {
      bf16x8 kf0 = *(const bf16x8*)&Ks[cur + (nt * 16 + l16) * 64 + ((quad ^ sx) * 8)];
      bf16x8 kf1 = *(const bf16x8*)&Ks[cur + (nt * 16 + l16) * 64 + (((4 + quad) ^ sx) * 8)];
#pragma unroll
      for (int mt = 0; mt < 2; ++mt) {
        f32x4 s = {};
        s = MFMA_BF16(kf0, qf[mt][0], s);
        s = MFMA_BF16(kf1, qf[mt][1], s);
        const float p0 = __builtin_amdgcn_exp2f(s[0]);
        const float p1 = __builtin_amdgcn_exp2f(s[1]);
        const float p2 = __builtin_amdgcn_exp2f(s[2]);
        const float p3 = __builtin_amdgcn_exp2f(s[3]);
        uint2 pk;
        pk.x = __builtin_amdgcn_perm(fbits(p1), fbits(p0), 0x07060302);  // [bf16(p1)|bf16(p0)]
        pk.y = __builtin_amdgcn_perm(fbits(p3), fbits(p2), 0x07060302);
        *(uint2*)&Ps[(w * 32 + mt * 16 + l16) * 64 +
                     (((nt * 2 + (quad >> 1)) ^ sx) * 8) + (quad & 1) * 4] = pk;
      }
    }

    // ---- O += P·V; row-sums via ones-B MFMA (sums truncated bf16 P -> bias cancels) ----
#pragma unroll
    for (int kc = 0; kc < 2; ++kc) {
      bf16x8 pf[2];
#pragma unroll
      for (int mt = 0; mt < 2; ++mt) {
        pf[mt] = *(const bf16x8*)&Ps[(w * 32 + mt * 16 + l16) * 64 + (((kc * 4 + quad) ^ sx) * 8)];
        lacc[mt] = MFMA_BF16(pf[mt], ones, lacc[mt]);
      }
#pragma unroll
      for (int dt = 0; dt < 4; ++dt) {
        bf16x8 vf = *(const bf16x8*)&VTs[cur + (dt * 16 + l16) * 64 + (((kc * 4 + quad) ^ sx) * 8)];
#pragma unroll
        for (int mt = 0; mt < 2; ++mt)
          oacc[mt][dt] = MFMA_BF16(pf[mt], vf, oacc[mt][dt]);
      }
    }
    __builtin_amdgcn_s_setprio(0);
  }

  // ---- normalize + store ----
#pragma unroll
  for (int mt = 0; mt < 2; ++mt) {
    float linv[4];
#pragma unroll
    for (int r = 0; r < 4; ++r) linv[r] = 1.0f / lacc[mt][r];
#pragma unroll
    for (int dt = 0; dt < 4; ++dt)
#pragma unroll
      for (int r = 0; r < 4; ++r)
        O[(size_t)(b * S + q0 + mt * 16 + quad * 4 + r) * HID + h * HD + dt * 16 + l16] =
            __float2bfloat16(oacc[mt][dt][r] * linv[r]);
  }
}

extern "C" void kernel_launch(void* const* d_in, const int* in_sizes, int n_in,
                              void* d_out, int out_size, void* d_ws, size_t ws_size,
                              hipStream_t stream) {
  const float* hidden = (const float*)d_in[0];
  const float* Wq = (const float*)d_in[1];
  const float* bq = (const float*)d_in[2];
  const float* Wk = (const float*)d_in[3];
  const float* bk = (const float*)d_in[4];
  const float* Wv = (const float*)d_in[5];
  const float* bv = (const float*)d_in[6];
  const float* Wo = (const float*)d_in[7];
  const float* bo = (const float*)d_in[8];
  float* out = (float*)d_out;

  constexpr int B = 2, S = 2048, HID = 2048, KV = 512, QKVN = 3072;
  constexpr int M = B * S;  // 4096
  const float c1 = 0.125f * 1.44269504089f;

  char* ws = (char*)d_ws;
  bf16_t* hiddenB = (bf16_t*)ws; ws += (size_t)M * HID * 2;
  bf16_t* WqkvT = (bf16_t*)ws;   ws += (size_t)QKVN * HID * 2;
  bf16_t* WoT = (bf16_t*)ws;     ws += (size_t)HID * HID * 2;
  bf16_t* qkv = (bf16_t*)ws;     ws += (size_t)M * QKVN * 2;
  bf16_t* vT = (bf16_t*)ws;      ws += (size_t)M * KV * 2;
  bf16_t* attn = (bf16_t*)ws;    ws += (size_t)M * HID * 2;
  float* bqkv = (float*)ws;      ws += QKVN * 4;

  // one fused prep launch: cast + 4 weight transposes (64x64 tiles) + bias concat
  prep<<<8192 + 2560 + 12, 256, 0, stream>>>(hidden, Wq, Wk, Wv, Wo, bq, bk, bv,
                                             hiddenB, WqkvT, WoT, bqkv, c1);

  // QKV projection: reverted to the proven 128^2 3-blocks/CU kernel (+XCD swizzle);
  // v-columns written transposed to vT in the epilogue
  gemm_bt<bf16_t><<<dim3(QKVN / 128, M / 128), 256, 0, stream>>>(
      hiddenB, WqkvT, bqkv, qkv, vT, M, QKVN, HID);

  // attention v9: 512 blocks (32 q-blocks x 8 KV-groups x B), 8 waves each
  gqa_attn<<<dim3(S / 64, 8, B), 512, 0, stream>>>(qkv, vT, attn);

  gemm_bt<float><<<dim3(HID / 128, M / 128), 256, 0, stream>>>(
      attn, WoT, bo, out, (bf16_t*)nullptr, M, HID, HID);
}

// Round 9
// 284.795 us; speedup vs baseline: 1.0985x; 1.0535x over previous
//
#include <hip/hip_runtime.h>
#include <hip/hip_bf16.h>
#include <math.h>

typedef __bf16 bf16x8 __attribute__((ext_vector_type(8)));
typedef float f32x4 __attribute__((ext_vector_type(4)));
typedef __hip_bfloat16 bf16_t;

#define MFMA_BF16(a, b, c) __builtin_amdgcn_mfma_f32_16x16x32_bf16((a), (b), (c), 0, 0, 0)

// async global->LDS, 16B per lane; LDS dest = wave-uniform base + lane*16
__device__ __forceinline__ void async_copy16(const bf16_t* g, bf16_t* lds_base) {
  __builtin_amdgcn_global_load_lds(
      (const __attribute__((address_space(1))) unsigned int*)g,
      (__attribute__((address_space(3))) unsigned int*)lds_base,
      16, 0, 0);
}

__device__ __forceinline__ unsigned fbits(float x) { return __builtin_bit_cast(unsigned, x); }

// ---------------- fused prep: cast hidden, transpose 4 weights, concat bias ----------------
// R9: transpose path vectorized (G13). Old: 16 scalar f32 loads + 16 scalar 2B stores per
// thread. New: 4x float4 loads -> LDS [64][65] (scalar writes, 2-way max = free; reads
// bank (tx4+j+i)%32 conflict-free) -> 4x ushort4 stores (128B/quarter-wave coalesced).
__global__ __launch_bounds__(256) void prep(
    const float* __restrict__ hidden, const float* __restrict__ Wq, const float* __restrict__ Wk,
    const float* __restrict__ Wv, const float* __restrict__ Wo,
    const float* __restrict__ bq, const float* __restrict__ bk, const float* __restrict__ bv,
    bf16_t* __restrict__ hiddenB, bf16_t* __restrict__ WqkvT, bf16_t* __restrict__ WoT,
    float* __restrict__ bqkv, float c1) {
  __shared__ float tile[64][65];
  int bid = blockIdx.x;
  const int t = threadIdx.x;
  if (bid < 8192) {  // cast hidden f32 -> bf16, float4 per thread
    const int i = bid * 256 + t;
    float4 v = ((const float4*)hidden)[i];
    union { bf16_t h[4]; ushort4 u; } cv;
    cv.h[0] = __float2bfloat16(v.x);
    cv.h[1] = __float2bfloat16(v.y);
    cv.h[2] = __float2bfloat16(v.z);
    cv.h[3] = __float2bfloat16(v.w);
    ((ushort4*)hiddenB)[i] = cv.u;
    return;
  }
  bid -= 8192;
  if (bid >= 2560) {  // bias concat: 12 blocks x 256 = 3072
    const int i = (bid - 2560) * 256 + t;
    float v;
    if (i < 2048) v = bq[i] * c1;
    else if (i < 2560) v = bk[i - 2048];
    else v = bv[i - 2560];
    bqkv[i] = v;
    return;
  }
  // weight transpose: in [2048][C] -> out [C][2048], 64x64 tiles (vectorized)
  const float* src;
  bf16_t* dst;
  int Cc, bx, by;
  float scale = 1.0f;
  if (bid < 1024) { src = Wq; dst = WqkvT; Cc = 2048; bx = bid & 31; by = bid >> 5; scale = c1; }
  else if (bid < 1280) { bid -= 1024; src = Wk; dst = WqkvT + (size_t)2048 * 2048; Cc = 512; bx = bid & 7; by = bid >> 3; }
  else if (bid < 1536) { bid -= 1280; src = Wv; dst = WqkvT + (size_t)2560 * 2048; Cc = 512; bx = bid & 7; by = bid >> 3; }
  else { bid -= 1536; src = Wo; dst = WoT; Cc = 2048; bx = bid & 31; by = bid >> 5; }
  const int tx4 = (t & 15) * 4, ty = t >> 4;  // 16x16 threads, 4 cols per thread
  const int c0 = bx * 64, r0 = by * 64;
#pragma unroll
  for (int p = 0; p < 4; ++p) {
    const int row = ty + p * 16;
    const float4 v = *(const float4*)&src[(size_t)(r0 + row) * Cc + c0 + tx4];
    tile[row][tx4] = v.x;
    tile[row][tx4 + 1] = v.y;
    tile[row][tx4 + 2] = v.z;
    tile[row][tx4 + 3] = v.w;
  }
  __syncthreads();
#pragma unroll
  for (int p = 0; p < 4; ++p) {
    const int i = ty + p * 16;
    union { bf16_t h[4]; ushort4 u; } cv;
#pragma unroll
    for (int j = 0; j < 4; ++j) cv.h[j] = __float2bfloat16(tile[tx4 + j][i] * scale);
    *(ushort4*)&dst[(size_t)(c0 + i) * 2048 + r0 + tx4] = cv.u;
  }
}

// ---------------- GEMM v7.1 (128^2, 2-barrier, 3 blocks/CU) + T1 XCD swizzle ----------------
// R7: reverted from 256^2 gemm256 (1 block/CU, MfmaUtil 25-29, 60% no-issue) to this
// proven structure — cross-block latency hiding (12 waves/CU) wins on this shape.
template <typename TOUT>
__global__ __launch_bounds__(256, 3) void gemm_bt(
    const bf16_t* __restrict__ A, const bf16_t* __restrict__ Bt,
    const float* __restrict__ bias, TOUT* __restrict__ C, bf16_t* __restrict__ vTp,
    int M, int N, int K) {
  __shared__ alignas(16) bf16_t As[128 * 64];
  __shared__ alignas(16) bf16_t Bs[128 * 64];

  const int tid = threadIdx.x;
  const int w = tid >> 6, lane = tid & 63;
  const int quad = lane >> 4, l16 = lane & 15;
  const int wm = w >> 1, wn = w & 1;

  // T1 bijective XCD swizzle (requires nwg % 8 == 0 — true for both call sites)
  const int nwg = gridDim.x * gridDim.y;
  const int flat = blockIdx.y * gridDim.x + blockIdx.x;
  const int swz = (flat & 7) * (nwg >> 3) + (flat >> 3);
  const int m0 = (swz / gridDim.x) * 128, n0 = (swz % gridDim.x) * 128;

  f32x4 acc[4][4] = {};

  const int rr = lane >> 3;                 // row within 8-row staging chunk
  const int scol = ((lane & 7) ^ rr) * 8;   // swizzled SOURCE col (bf16 units)
  const int sx = l16 & 7;                   // row&7 for fragment reads

  for (int k0 = 0; k0 < K; k0 += 64) {
    __syncthreads();
#pragma unroll
    for (int c = 0; c < 4; ++c) {
      const int r = w * 32 + c * 8 + rr;
      async_copy16(A + (size_t)(m0 + r) * K + k0 + scol, &As[(w * 32 + c * 8) * 64]);
      async_copy16(Bt + (size_t)(n0 + r) * K + k0 + scol, &Bs[(w * 32 + c * 8) * 64]);
    }
    __syncthreads();

#pragma unroll
    for (int kh = 0; kh < 2; ++kh) {
      bf16x8 af[4], bf[4];
#pragma unroll
      for (int i = 0; i < 4; ++i) {
        af[i] = *(const bf16x8*)&As[(wm * 64 + i * 16 + l16) * 64 + (((kh * 4 + quad) ^ sx) * 8)];
        bf[i] = *(const bf16x8*)&Bs[(wn * 64 + i * 16 + l16) * 64 + (((kh * 4 + quad) ^ sx) * 8)];
      }
#pragma unroll
      for (int i = 0; i < 4; ++i)
#pragma unroll
        for (int j = 0; j < 4; ++j)
          acc[i][j] = MFMA_BF16(af[i], bf[j], acc[i][j]);
    }
  }

  if (vTp != nullptr && n0 >= 2560) {
    // v-columns -> vT[b][col-2560][s]; rows here are b*2048+s with 4 consecutive s per lane
#pragma unroll
    for (int i = 0; i < 4; ++i) {
      const int row = m0 + wm * 64 + i * 16 + quad * 4;
      const int bb = row >> 11, s = row & 2047;
#pragma unroll
      for (int j = 0; j < 4; ++j) {
        const int col = n0 + wn * 64 + j * 16 + l16;
        const float bv = bias[col];
        union { bf16_t h[4]; ushort4 u; } cv;
#pragma unroll
        for (int r = 0; r < 4; ++r) cv.h[r] = __float2bfloat16(acc[i][j][r] + bv);
        *(ushort4*)&vTp[((size_t)bb * 512 + (col - 2560)) * 2048 + s] = cv.u;
      }
    }
    return;
  }

#pragma unroll
  for (int i = 0; i < 4; ++i) {
    const int row = m0 + wm * 64 + i * 16 + quad * 4;
#pragma unroll
    for (int j = 0; j < 4; ++j) {
      const int col = n0 + wn * 64 + j * 16 + l16;
      const float bv = bias[col];
#pragma unroll
      for (int r = 0; r < 4; ++r) {
        const float val = acc[i][j][r] + bv;
        if constexpr (__is_same(TOUT, float)) {
          C[(size_t)(row + r) * N + col] = val;
        } else {
          C[(size_t)(row + r) * N + col] = __float2bfloat16(val);
        }
      }
    }
  }
}

// ---------------- GQA flash attention v9: 4-head KV sharing + LDS double-buffer ----------------
// Block = 64 q-rows x 4 heads (one full KV group g = blockIdx.y), 8 waves/512 thr.
// R8: 76.0us, MfmaUtil 43.6 + VALUBusy 44.7 = 88% issue utilization — near structural
// ceiling. Checked alternatives: dropping K/V staging -> 35 TB/s L2 demand (at ceiling;
// staging amortizes 8 waves here, unlike m169's 1-wave case); KVBLK=128 -> 1 block/CU
// occupancy trap. FROZEN.
__global__ __launch_bounds__(512, 2) void gqa_attn(
    const bf16_t* __restrict__ QKV, const bf16_t* __restrict__ VT, bf16_t* __restrict__ O) {
  constexpr int S = 2048, HID = 2048, QKVS = 3072, HD = 64;
  const int tid = threadIdx.x;
  const int w = tid >> 6, lane = tid & 63;
  const int quad = lane >> 4, l16 = lane & 15;
  const int g = blockIdx.y, b = blockIdx.z;
  const int h = g * 4 + (w & 3);                   // wave's head (rep=4 GQA mapping)
  const int q0 = blockIdx.x * 64 + (w >> 2) * 32;  // wave's 32 q rows

  __shared__ alignas(16) bf16_t Ks[2 * 64 * 64];
  __shared__ alignas(16) bf16_t VTs[2 * 64 * 64];
  __shared__ alignas(16) bf16_t Ps[256 * 64];

  // Q fragments in registers (B-operand layout: n=l16 -> q, k=quad*8+j); pre-scaled
  bf16x8 qf[2][2];
#pragma unroll
  for (int mt = 0; mt < 2; ++mt)
#pragma unroll
    for (int ks = 0; ks < 2; ++ks)
      qf[mt][ks] = *(const bf16x8*)&QKV[(size_t)(b * S + q0 + mt * 16 + l16) * QKVS +
                                        h * HD + ks * 32 + quad * 8];

  const int rr = lane >> 3, c7 = lane & 7;
  const int sx = l16 & 7;

  const bf16_t* Kbase = QKV + (size_t)b * S * QKVS + 2048 + g * HD;
  const bf16_t* Vbase = VT + (size_t)(b * 512 + g * HD) * S;

  // staging: 8 waves x 8 rows — thread owns row srow = w*8+rr, 16B chunk c7.
  // LDS dest chunk XOR-swizzled with row&7 (= rr); read side uses l16&7 (= sx): consistent.
  const int srow = w * 8 + rr;
  const bf16_t* kp = Kbase + (size_t)srow * QKVS + c7 * 8;
  const bf16_t* vp = Vbase + (size_t)srow * S + c7 * 8;
  const int woff = srow * 64 + (c7 ^ rr) * 8;  // within-buffer LDS write offset

  f32x4 oacc[2][4] = {};
  f32x4 lacc[2] = {};
  bf16x8 ones;
#pragma unroll
  for (int j = 0; j < 8; ++j) ones[j] = (__bf16)1.0f;

  // prologue: tile 0 -> regs
  uint4 kr = *(const uint4*)kp;
  uint4 vr = *(const uint4*)vp;

  for (int it = 0; it < 32; ++it) {
    const int cur = (it & 1) * (64 * 64);
    // write tile `it`; prefetch tile it+1 (wraps harmlessly on last iter)
    *(uint4*)&Ks[cur + woff] = kr;
    *(uint4*)&VTs[cur + woff] = vr;
    const int sn = ((it + 1) & 31) * 64;
    kr = *(const uint4*)(kp + (size_t)sn * QKVS);
    vr = *(const uint4*)(vp + sn);
    __syncthreads();  // tile `it` visible; all reads of buf[(it+1)&1] (iter it-1) done

    __builtin_amdgcn_s_setprio(1);
    // ---- S^T = K·Q^T (row=kv=quad*4+r, col=q=l16); p=exp2(s); pack(trunc) -> Ps[q][kv] ----
#pragma unroll
    for (int nt = 0; nt < 4; ++nt) {
      bf16x8 kf0 = *(const bf16x8*)&Ks[cur + (nt * 16 + l16) * 64 + ((quad ^ sx) * 8)];
      bf16x8 kf1 = *(const bf16x8*)&Ks[cur + (nt * 16 + l16) * 64 + (((4 + quad) ^ sx) * 8)];
#pragma unroll
      for (int mt = 0; mt < 2; ++mt) {
        f32x4 s = {};
        s = MFMA_BF16(kf0, qf[mt][0], s);
        s = MFMA_BF16(kf1, qf[mt][1], s);
        const float p0 = __builtin_amdgcn_exp2f(s[0]);
        const float p1 = __builtin_amdgcn_exp2f(s[1]);
        const float p2 = __builtin_amdgcn_exp2f(s[2]);
        const float p3 = __builtin_amdgcn_exp2f(s[3]);
        uint2 pk;
        pk.x = __builtin_amdgcn_perm(fbits(p1), fbits(p0), 0x07060302);  // [bf16(p1)|bf16(p0)]
        pk.y = __builtin_amdgcn_perm(fbits(p3), fbits(p2), 0x07060302);
        *(uint2*)&Ps[(w * 32 + mt * 16 + l16) * 64 +
                     (((nt * 2 + (quad >> 1)) ^ sx) * 8) + (quad & 1) * 4] = pk;
      }
    }

    // ---- O += P·V; row-sums via ones-B MFMA (sums truncated bf16 P -> bias cancels) ----
#pragma unroll
    for (int kc = 0; kc < 2; ++kc) {
      bf16x8 pf[2];
#pragma unroll
      for (int mt = 0; mt < 2; ++mt) {
        pf[mt] = *(const bf16x8*)&Ps[(w * 32 + mt * 16 + l16) * 64 + (((kc * 4 + quad) ^ sx) * 8)];
        lacc[mt] = MFMA_BF16(pf[mt], ones, lacc[mt]);
      }
#pragma unroll
      for (int dt = 0; dt < 4; ++dt) {
        bf16x8 vf = *(const bf16x8*)&VTs[cur + (dt * 16 + l16) * 64 + (((kc * 4 + quad) ^ sx) * 8)];
#pragma unroll
        for (int mt = 0; mt < 2; ++mt)
          oacc[mt][dt] = MFMA_BF16(pf[mt], vf, oacc[mt][dt]);
      }
    }
    __builtin_amdgcn_s_setprio(0);
  }

  // ---- normalize + store ----
#pragma unroll
  for (int mt = 0; mt < 2; ++mt) {
    float linv[4];
#pragma unroll
    for (int r = 0; r < 4; ++r) linv[r] = 1.0f / lacc[mt][r];
#pragma unroll
    for (int dt = 0; dt < 4; ++dt)
#pragma unroll
      for (int r = 0; r < 4; ++r)
        O[(size_t)(b * S + q0 + mt * 16 + quad * 4 + r) * HID + h * HD + dt * 16 + l16] =
            __float2bfloat16(oacc[mt][dt][r] * linv[r]);
  }
}

extern "C" void kernel_launch(void* const* d_in, const int* in_sizes, int n_in,
                              void* d_out, int out_size, void* d_ws, size_t ws_size,
                              hipStream_t stream) {
  const float* hidden = (const float*)d_in[0];
  const float* Wq = (const float*)d_in[1];
  const float* bq = (const float*)d_in[2];
  const float* Wk = (const float*)d_in[3];
  const float* bk = (const float*)d_in[4];
  const float* Wv = (const float*)d_in[5];
  const float* bv = (const float*)d_in[6];
  const float* Wo = (const float*)d_in[7];
  const float* bo = (const float*)d_in[8];
  float* out = (float*)d_out;

  constexpr int B = 2, S = 2048, HID = 2048, KV = 512, QKVN = 3072;
  constexpr int M = B * S;  // 4096
  const float c1 = 0.125f * 1.44269504089f;

  char* ws = (char*)d_ws;
  bf16_t* hiddenB = (bf16_t*)ws; ws += (size_t)M * HID * 2;
  bf16_t* WqkvT = (bf16_t*)ws;   ws += (size_t)QKVN * HID * 2;
  bf16_t* WoT = (bf16_t*)ws;     ws += (size_t)HID * HID * 2;
  bf16_t* qkv = (bf16_t*)ws;     ws += (size_t)M * QKVN * 2;
  bf16_t* vT = (bf16_t*)ws;      ws += (size_t)M * KV * 2;
  bf16_t* attn = (bf16_t*)ws;    ws += (size_t)M * HID * 2;
  float* bqkv = (float*)ws;      ws += QKVN * 4;

  // one fused prep launch: cast + 4 weight transposes (64x64 tiles) + bias concat
  prep<<<8192 + 2560 + 12, 256, 0, stream>>>(hidden, Wq, Wk, Wv, Wo, bq, bk, bv,
                                             hiddenB, WqkvT, WoT, bqkv, c1);

  // QKV projection (128^2 3-blocks/CU + XCD swizzle); v-columns written transposed to vT
  gemm_bt<bf16_t><<<dim3(QKVN / 128, M / 128), 256, 0, stream>>>(
      hiddenB, WqkvT, bqkv, qkv, vT, M, QKVN, HID);

  // attention v9: 512 blocks (32 q-blocks x 8 KV-groups x B), 8 waves each
  gqa_attn<<<dim3(S / 64, 8, B), 512, 0, stream>>>(qkv, vT, attn);

  gemm_bt<float><<<dim3(HID / 128, M / 128), 256, 0, stream>>>(
      attn, WoT, bo, out, (bf16_t*)nullptr, M, HID, HID);
}